// Round 12
// baseline (582.420 us; speedup 1.0000x reference)
//
#include <hip/hip_runtime.h>

#define N_ENT 50000
#define N_REL 500
#define N_EDGE 500000
#define HEADS 2
#define DIM 64
#define POW_ITER 3
#define ALPHA 0.15f
#define LN_EPS 1e-5f
#define NBLK 49  // ceil(N_ENT/1024)

typedef unsigned uv4 __attribute__((ext_vector_type(4)));

// bf16 round-to-nearest-even pack
static __device__ __forceinline__ unsigned bf16_rne(float f) {
  unsigned u = __float_as_uint(f);
  return (u + 0x7FFFu + ((u >> 16) & 1u)) >> 16;
}

// ================= CSR build (once per launch; graph is layer-invariant) =================
__global__ void deg_kernel(const int* __restrict__ src, int* __restrict__ deg) {
  int e = blockIdx.x * blockDim.x + threadIdx.x;
  if (e >= N_EDGE) return;
  atomicAdd(&deg[src[e]], 1);
}

__global__ __launch_bounds__(1024) void scan1_kernel(const int* __restrict__ deg,
                                                     int* __restrict__ exc,
                                                     int* __restrict__ bsum) {
  __shared__ int tmp[1024];
  int tid = threadIdx.x;
  int i = blockIdx.x * 1024 + tid;
  int v = (i < N_ENT) ? deg[i] : 0;
  tmp[tid] = v;
  __syncthreads();
  for (int off = 1; off < 1024; off <<= 1) {
    int t = (tid >= off) ? tmp[tid - off] : 0;
    __syncthreads();
    tmp[tid] += t;
    __syncthreads();
  }
  if (i < N_ENT) exc[i] = tmp[tid] - v;
  if (tid == 1023) bsum[blockIdx.x] = tmp[1023];
}

__global__ void scan2_kernel(const int* __restrict__ bsum, int* __restrict__ boff) {
  int t = threadIdx.x;  // 64 threads
  int v = (t < NBLK) ? bsum[t] : 0;
  int incl = v;
#pragma unroll
  for (int off = 1; off < 64; off <<= 1) {
    int u = __shfl_up(incl, off);
    if (t >= off) incl += u;
  }
  if (t < NBLK) boff[t] = incl - v;
  if (t == NBLK - 1) boff[NBLK] = incl;
}

__global__ __launch_bounds__(1024) void scan3_kernel(const int* __restrict__ exc,
                                                     const int* __restrict__ boff,
                                                     int* __restrict__ rowptr) {
  int i = blockIdx.x * 1024 + threadIdx.x;
  if (i < N_ENT) rowptr[i] = exc[i] + boff[i >> 10];
  if (i == N_ENT) rowptr[N_ENT] = boff[NBLK];
}

// scatter: csr_src/csr_dst/csr_et in CSR position order
__global__ void scatter_kernel(const int* __restrict__ src, const int* __restrict__ dst,
                               const int* __restrict__ et, int* __restrict__ cursor,
                               int* __restrict__ csr_src, int* __restrict__ csr_dst,
                               int* __restrict__ csr_et) {
  int e = blockIdx.x * blockDim.x + threadIdx.x;
  if (e >= N_EDGE) return;
  int s = src[e];
  int p = atomicAdd(&cursor[s], 1);
  csr_src[p] = s;
  csr_dst[p] = dst[e];
  csr_et[p] = et[e];
}

// ================= LayerNorm: one wave per node; writes f32 h and bf16 h_bf =================
__global__ void ln_kernel(const float* __restrict__ x, const float* __restrict__ g,
                          const float* __restrict__ b, float* __restrict__ h,
                          unsigned short* __restrict__ h_bf) {
  int wid = (blockIdx.x * blockDim.x + threadIdx.x) >> 6;
  int lane = threadIdx.x & 63;
  if (wid >= N_ENT) return;
  float v = x[wid * 64 + lane];
  float s = v;
#pragma unroll
  for (int off = 32; off; off >>= 1) s += __shfl_xor(s, off);
  float mu = s * (1.0f / 64.0f);
  float d = v - mu;
  float s2 = d * d;
#pragma unroll
  for (int off = 32; off; off >>= 1) s2 += __shfl_xor(s2, off);
  float rs = rsqrtf(s2 * (1.0f / 64.0f) + LN_EPS);
  float hv = d * rs * g[lane] + b[lane];
  h[wid * 64 + lane] = hv;
  h_bf[wid * 64 + lane] = (unsigned short)bf16_rne(hv);
}

// ================= node scores: W staged in LDS as float4 (2 ks x 2 cols); 2 nodes/wave =================
__global__ __launch_bounds__(256) void scores_kernel(
    const float* __restrict__ x, const float* __restrict__ W,
    const float* __restrict__ att, float* __restrict__ s_out, int M) {
  __shared__ float4 WP4[32][64];
  for (int i = threadIdx.x; i < 32 * 64; i += 256) {
    int k2 = i >> 6, j = i & 63;
    WP4[k2][j] = make_float4(W[(2 * k2) * 128 + j], W[(2 * k2) * 128 + j + 64],
                             W[(2 * k2 + 1) * 128 + j], W[(2 * k2 + 1) * 128 + j + 64]);
  }
  __syncthreads();
  int lane = threadIdx.x & 63;
  float a0v = att[lane], a1v = att[lane + 64];
  int gw = (blockIdx.x * 256 + threadIdx.x) >> 6;
  int nw = (gridDim.x * 256) >> 6;
  for (int n0 = 2 * gw; n0 < M; n0 += 2 * nw) {
    int nu = __builtin_amdgcn_readfirstlane(n0);
    const float* xr0 = x + nu * 64;
    const float* xr1 = x + (nu + 1) * 64;
    float a00 = 0.f, a01 = 0.f, a10 = 0.f, a11 = 0.f;
#pragma unroll 8
    for (int k2 = 0; k2 < 32; ++k2) {
      float4 wv = WP4[k2][lane];
      float xa0 = xr0[2 * k2], xa1 = xr0[2 * k2 + 1];
      float xb0 = xr1[2 * k2], xb1 = xr1[2 * k2 + 1];
      a00 += xa0 * wv.x + xa1 * wv.z;
      a01 += xa0 * wv.y + xa1 * wv.w;
      a10 += xb0 * wv.x + xb1 * wv.z;
      a11 += xb0 * wv.y + xb1 * wv.w;
    }
    float t00 = tanhf(a00) * a0v, t01 = tanhf(a01) * a1v;
    float t10 = tanhf(a10) * a0v, t11 = tanhf(a11) * a1v;
#pragma unroll
    for (int off = 32; off; off >>= 1) {
      t00 += __shfl_xor(t00, off);
      t01 += __shfl_xor(t01, off);
      t10 += __shfl_xor(t10, off);
      t11 += __shfl_xor(t11, off);
    }
    if (lane == 0) {
      ((float2*)s_out)[nu] = make_float2(t00, t01);
      ((float2*)s_out)[nu + 1] = make_float2(t10, t11);
    }
  }
}

// ================= edge weights: per CSR position (coalesced) =================
__global__ void edge_w_kernel(const int* __restrict__ csr_src, const int* __restrict__ csr_dst,
                              const int* __restrict__ csr_et, const float* __restrict__ s_h,
                              const float* __restrict__ s_t, const float* __restrict__ s_r,
                              float* __restrict__ csr_w) {
  int p = blockIdx.x * blockDim.x + threadIdx.x;
  if (p >= N_EDGE) return;
  int s = csr_src[p], d = csr_dst[p], r = csr_et[p];
  float2 a = ((const float2*)s_h)[s];
  float2 b = ((const float2*)s_t)[d];
  float2 c = ((const float2*)s_r)[r];
  float sc0 = a.x + b.x + c.x;
  float sc1 = a.y + b.y + c.y;
  sc0 = (sc0 >= 0.f) ? sc0 : 0.01f * sc0;
  sc1 = (sc1 >= 0.f) ? sc1 : 0.01f * sc1;
  ((float2*)csr_w)[p] = make_float2(expf(sc0), expf(sc1));
}

// ================= cinv: wave per node, segmented sum over contiguous csr_w =================
__global__ __launch_bounds__(256) void cinv_kernel(const int* __restrict__ rowptr,
                                                   const float* __restrict__ csr_w,
                                                   float* __restrict__ cinv) {
  int n = (blockIdx.x * 256 + threadIdx.x) >> 6;
  int lane = threadIdx.x & 63;
  if (n >= N_ENT) return;
  int p0 = rowptr[n], p1 = rowptr[n + 1];
  float z0 = 0.f, z1 = 0.f;
  for (int p = p0 + lane; p < p1; p += 64) {
    float2 w2 = ((const float2*)csr_w)[p];
    z0 += w2.x;
    z1 += w2.y;
  }
#pragma unroll
  for (int off = 32; off; off >>= 1) {
    z0 += __shfl_xor(z0, off);
    z1 += __shfl_xor(z1, off);
  }
  if (lane == 0) {
    float c0 = (p1 > p0) ? (1.0f - ALPHA) / z0 : 0.f;
    float c1 = (p1 > p0) ? (1.0f - ALPHA) / z1 : 0.f;
    ((float2*)cinv)[n] = make_float2(c0, c1);
  }
}

// ================= monolithic CSR SpMM: wave per node; 4 edge slots x 8 dims/lane =================
template <int IN_H>
__global__ __launch_bounds__(256) void spmm_kernel(
    const int* __restrict__ rowptr, const int* __restrict__ csr_dst,
    const float* __restrict__ csr_w, const float* __restrict__ cinv,
    const float* __restrict__ h, const unsigned short* __restrict__ Zin_b,
    unsigned short* __restrict__ Zout_b) {
  int lane = threadIdx.x & 63;
  int slot = lane >> 4;
  int l16 = lane & 15;
  int hh = l16 >> 3;
  int hoff = 8 * (l16 & 7);
  int gw = (blockIdx.x * 256 + threadIdx.x) >> 6;
  int nw = (gridDim.x * 256) >> 6;
  for (int n = gw; n < N_ENT; n += nw) {
    int p0 = rowptr[n], p1 = rowptr[n + 1];
    float acc[8];
#pragma unroll
    for (int j = 0; j < 8; ++j) acc[j] = 0.f;
    for (int p = p0 + slot; p < p1; p += 4) {
      int d = csr_dst[p];
      float2 w2 = ((const float2*)csr_w)[p];
      float a = hh ? w2.y : w2.x;
      uv4 q;
      if (IN_H) {
        q = *(const uv4*)(Zin_b + d * 64 + hoff);
      } else {
        q = *(const uv4*)(Zin_b + d * 128 + 8 * l16);
      }
      acc[0] += a * __uint_as_float(q.x << 16);
      acc[1] += a * __uint_as_float(q.x & 0xFFFF0000u);
      acc[2] += a * __uint_as_float(q.y << 16);
      acc[3] += a * __uint_as_float(q.y & 0xFFFF0000u);
      acc[4] += a * __uint_as_float(q.z << 16);
      acc[5] += a * __uint_as_float(q.z & 0xFFFF0000u);
      acc[6] += a * __uint_as_float(q.w << 16);
      acc[7] += a * __uint_as_float(q.w & 0xFFFF0000u);
    }
#pragma unroll
    for (int j = 0; j < 8; ++j) {
      acc[j] += __shfl_xor(acc[j], 16);
      acc[j] += __shfl_xor(acc[j], 32);
    }
    if (slot == 0) {
      float c = cinv[n * 2 + hh];
      const float* hp = h + n * 64 + hoff;
      float o[8];
#pragma unroll
      for (int j = 0; j < 8; ++j) o[j] = ALPHA * hp[j] + c * acc[j];
      uv4 qo;
      qo.x = bf16_rne(o[0]) | (bf16_rne(o[1]) << 16);
      qo.y = bf16_rne(o[2]) | (bf16_rne(o[3]) << 16);
      qo.z = bf16_rne(o[4]) | (bf16_rne(o[5]) << 16);
      qo.w = bf16_rne(o[6]) | (bf16_rne(o[7]) << 16);
      *(uv4*)(Zout_b + n * 128 + 8 * l16) = qo;
    }
  }
}

// ================= output: W_o in LDS float4 [32][64]; lane = col j; 8 independent FMA chains =====
__global__ __launch_bounds__(256) void out_kernel(
    const unsigned short* __restrict__ Zb, const float* __restrict__ Wo,
    const float* __restrict__ x, float* __restrict__ out) {
  __shared__ float4 Wos4[32][64];  // Wos4[c4][j] = Wo[4c4..4c4+3][j]
  for (int i = threadIdx.x; i < 32 * 64; i += 256) {
    int c4 = i >> 6, j = i & 63;
    Wos4[c4][j] = make_float4(Wo[(4 * c4 + 0) * 64 + j], Wo[(4 * c4 + 1) * 64 + j],
                              Wo[(4 * c4 + 2) * 64 + j], Wo[(4 * c4 + 3) * 64 + j]);
  }
  __syncthreads();
  int lane = threadIdx.x & 63;
  int gw = (blockIdx.x * 256 + threadIdx.x) >> 6;
  int nw = (gridDim.x * 256) >> 6;
  for (int n = gw; n < N_ENT; n += nw) {
    const uv4* zr = (const uv4*)(Zb + (size_t)n * 128);  // 128 bf16 = 16 uv4
    float ac0 = 0.f, ac1 = 0.f, ac2 = 0.f, ac3 = 0.f;
    float ac4 = 0.f, ac5 = 0.f, ac6 = 0.f, ac7 = 0.f;
#pragma unroll
    for (int i = 0; i < 16; ++i) {
      uv4 q = zr[i];
      float4 wA = Wos4[2 * i][lane];      // dims 8i+0..3
      float4 wB = Wos4[2 * i + 1][lane];  // dims 8i+4..7
      ac0 += __uint_as_float(q.x << 16) * wA.x;
      ac1 += __uint_as_float(q.x & 0xFFFF0000u) * wA.y;
      ac2 += __uint_as_float(q.y << 16) * wA.z;
      ac3 += __uint_as_float(q.y & 0xFFFF0000u) * wA.w;
      ac4 += __uint_as_float(q.z << 16) * wB.x;
      ac5 += __uint_as_float(q.z & 0xFFFF0000u) * wB.y;
      ac6 += __uint_as_float(q.w << 16) * wB.z;
      ac7 += __uint_as_float(q.w & 0xFFFF0000u) * wB.w;
    }
    float acc = ((ac0 + ac1) + (ac2 + ac3)) + ((ac4 + ac5) + (ac6 + ac7));
    out[n * 64 + lane] = acc + x[n * 64 + lane];
  }
}

extern "C" void kernel_launch(void* const* d_in, const int* in_sizes, int n_in,
                              void* d_out, int out_size, void* d_ws, size_t ws_size,
                              hipStream_t stream) {
  const float* ent0 = (const float*)d_in[0];
  const float* rel  = (const float*)d_in[1];
  const int* eidx   = (const int*)d_in[2];
  const int* src    = eidx;
  const int* dst    = eidx + N_EDGE;
  const int* et     = (const int*)d_in[3];
  const float* gam  = (const float*)d_in[4];
  const float* bet  = (const float*)d_in[5];
  const float* W_h  = (const float*)d_in[6];
  const float* W_t  = (const float*)d_in[7];
  const float* W_r  = (const float*)d_in[8];
  const float* att_h = (const float*)d_in[9];
  const float* att_t = (const float*)d_in[10];
  const float* att_r = (const float*)d_in[11];
  const float* W_o  = (const float*)d_in[12];
  float* outp = (float*)d_out;

  char* w = (char*)d_ws;
  auto alloc = [&](size_t bytes) {
    char* p = w;
    w += (bytes + 255) & ~(size_t)255;
    return p;
  };
  float* ent1   = (float*)alloc((size_t)N_ENT * 64 * 4);
  float* h      = (float*)alloc((size_t)N_ENT * 64 * 4);
  unsigned short* h_bf = (unsigned short*)alloc((size_t)N_ENT * 64 * 2);
  float* s_h    = (float*)alloc((size_t)N_ENT * 2 * 4);
  float* s_t    = (float*)alloc((size_t)N_ENT * 2 * 4);
  float* s_r    = (float*)alloc((size_t)N_REL * 2 * 4);
  float* cinv   = (float*)alloc((size_t)N_ENT * 2 * 4);
  float* csr_w  = (float*)alloc((size_t)N_EDGE * 2 * 4);
  unsigned short* Zb0 = (unsigned short*)alloc((size_t)N_ENT * 128 * 2);
  unsigned short* Zb1 = (unsigned short*)alloc((size_t)N_ENT * 128 * 2);
  int* deg      = (int*)alloc((size_t)N_ENT * 4);
  int* exc      = (int*)alloc((size_t)N_ENT * 4);
  int* bsum     = (int*)alloc((size_t)NBLK * 4);
  int* boff     = (int*)alloc((size_t)(NBLK + 1) * 4);
  int* rowptr   = (int*)alloc((size_t)(N_ENT + 1) * 4);
  int* cursor   = (int*)alloc((size_t)N_ENT * 4);
  int* csr_src  = (int*)alloc((size_t)N_EDGE * 4);
  int* csr_dst  = (int*)alloc((size_t)N_EDGE * 4);
  int* csr_et   = (int*)alloc((size_t)N_EDGE * 4);

  const int EB = (N_EDGE + 255) / 256;

  // ---- CSR build ----
  hipMemsetAsync(deg, 0, (size_t)N_ENT * 4, stream);
  deg_kernel<<<EB, 256, 0, stream>>>(src, deg);
  scan1_kernel<<<NBLK, 1024, 0, stream>>>(deg, exc, bsum);
  scan2_kernel<<<1, 64, 0, stream>>>(bsum, boff);
  scan3_kernel<<<NBLK, 1024, 0, stream>>>(exc, boff, rowptr);
  hipMemcpyAsync(cursor, rowptr, (size_t)N_ENT * 4, hipMemcpyDeviceToDevice, stream);
  scatter_kernel<<<EB, 256, 0, stream>>>(src, dst, et, cursor, csr_src, csr_dst, csr_et);

  for (int l = 0; l < 2; ++l) {
    const float* x = (l == 0) ? ent0 : ent1;
    float* y = (l == 0) ? ent1 : outp;

    ln_kernel<<<(N_ENT + 3) / 4, 256, 0, stream>>>(x, gam + l * 64, bet + l * 64, h, h_bf);
    scores_kernel<<<512, 256, 0, stream>>>(h, W_h + l * 8192, att_h + l * 128, s_h, N_ENT);
    scores_kernel<<<512, 256, 0, stream>>>(h, W_t + l * 8192, att_t + l * 128, s_t, N_ENT);
    scores_kernel<<<8, 256, 0, stream>>>(rel, W_r + l * 8192, att_r + l * 128, s_r, N_REL);

    edge_w_kernel<<<EB, 256, 0, stream>>>(csr_src, csr_dst, csr_et, s_h, s_t, s_r, csr_w);
    cinv_kernel<<<(N_ENT * 64 + 255) / 256, 256, 0, stream>>>(rowptr, csr_w, cinv);

    // ---- PPR power iteration: h_bf -> Zb0 -> Zb1 -> Zb0 (all bf16) ----
    spmm_kernel<1><<<2048, 256, 0, stream>>>(rowptr, csr_dst, csr_w, cinv, h, h_bf, Zb0);
    spmm_kernel<0><<<2048, 256, 0, stream>>>(rowptr, csr_dst, csr_w, cinv, h, Zb0, Zb1);
    spmm_kernel<0><<<2048, 256, 0, stream>>>(rowptr, csr_dst, csr_w, cinv, h, Zb1, Zb0);

    out_kernel<<<1280, 256, 0, stream>>>(Zb0, W_o + l * 8192, x, y);
  }
}

// Round 13
// 500.539 us; speedup vs baseline: 1.1636x; 1.1636x over previous
//
#include <hip/hip_runtime.h>

#define N_ENT 50000
#define N_REL 500
#define N_EDGE 500000
#define HEADS 2
#define DIM 64
#define POW_ITER 3
#define ALPHA 0.15f
#define LN_EPS 1e-5f
#define NBLK 49  // ceil(N_ENT/1024)

typedef unsigned uv4 __attribute__((ext_vector_type(4)));
typedef short bf16x8 __attribute__((ext_vector_type(8)));
typedef float f32x4 __attribute__((ext_vector_type(4)));

// bf16 round-to-nearest-even pack
static __device__ __forceinline__ unsigned bf16_rne(float f) {
  unsigned u = __float_as_uint(f);
  return (u + 0x7FFFu + ((u >> 16) & 1u)) >> 16;
}

// ================= CSR build (once per launch; graph is layer-invariant) =================
__global__ void deg_kernel(const int* __restrict__ src, int* __restrict__ deg) {
  int e = blockIdx.x * blockDim.x + threadIdx.x;
  if (e >= N_EDGE) return;
  atomicAdd(&deg[src[e]], 1);
}

__global__ __launch_bounds__(1024) void scan1_kernel(const int* __restrict__ deg,
                                                     int* __restrict__ exc,
                                                     int* __restrict__ bsum) {
  __shared__ int tmp[1024];
  int tid = threadIdx.x;
  int i = blockIdx.x * 1024 + tid;
  int v = (i < N_ENT) ? deg[i] : 0;
  tmp[tid] = v;
  __syncthreads();
  for (int off = 1; off < 1024; off <<= 1) {
    int t = (tid >= off) ? tmp[tid - off] : 0;
    __syncthreads();
    tmp[tid] += t;
    __syncthreads();
  }
  if (i < N_ENT) exc[i] = tmp[tid] - v;
  if (tid == 1023) bsum[blockIdx.x] = tmp[1023];
}

__global__ void scan2_kernel(const int* __restrict__ bsum, int* __restrict__ boff) {
  int t = threadIdx.x;  // 64 threads
  int v = (t < NBLK) ? bsum[t] : 0;
  int incl = v;
#pragma unroll
  for (int off = 1; off < 64; off <<= 1) {
    int u = __shfl_up(incl, off);
    if (t >= off) incl += u;
  }
  if (t < NBLK) boff[t] = incl - v;
  if (t == NBLK - 1) boff[NBLK] = incl;
}

__global__ __launch_bounds__(1024) void scan3_kernel(const int* __restrict__ exc,
                                                     const int* __restrict__ boff,
                                                     int* __restrict__ rowptr) {
  int i = blockIdx.x * 1024 + threadIdx.x;
  if (i < N_ENT) rowptr[i] = exc[i] + boff[i >> 10];
  if (i == N_ENT) rowptr[N_ENT] = boff[NBLK];
}

// scatter: csr_src/csr_dst/csr_et in CSR position order
__global__ void scatter_kernel(const int* __restrict__ src, const int* __restrict__ dst,
                               const int* __restrict__ et, int* __restrict__ cursor,
                               int* __restrict__ csr_src, int* __restrict__ csr_dst,
                               int* __restrict__ csr_et) {
  int e = blockIdx.x * blockDim.x + threadIdx.x;
  if (e >= N_EDGE) return;
  int s = src[e];
  int p = atomicAdd(&cursor[s], 1);
  csr_src[p] = s;
  csr_dst[p] = dst[e];
  csr_et[p] = et[e];
}

// ================= LayerNorm: one wave per node; writes f32 h and bf16 h_bf =================
__global__ void ln_kernel(const float* __restrict__ x, const float* __restrict__ g,
                          const float* __restrict__ b, float* __restrict__ h,
                          unsigned short* __restrict__ h_bf) {
  int wid = (blockIdx.x * blockDim.x + threadIdx.x) >> 6;
  int lane = threadIdx.x & 63;
  if (wid >= N_ENT) return;
  float v = x[wid * 64 + lane];
  float s = v;
#pragma unroll
  for (int off = 32; off; off >>= 1) s += __shfl_xor(s, off);
  float mu = s * (1.0f / 64.0f);
  float d = v - mu;
  float s2 = d * d;
#pragma unroll
  for (int off = 32; off; off >>= 1) s2 += __shfl_xor(s2, off);
  float rs = rsqrtf(s2 * (1.0f / 64.0f) + LN_EPS);
  float hv = d * rs * g[lane] + b[lane];
  h[wid * 64 + lane] = hv;
  h_bf[wid * 64 + lane] = (unsigned short)bf16_rne(hv);
}

// ================= node scores: W staged in LDS as float4 (2 ks x 2 cols); 2 nodes/wave =================
__global__ __launch_bounds__(256) void scores_kernel(
    const float* __restrict__ x, const float* __restrict__ W,
    const float* __restrict__ att, float* __restrict__ s_out, int M) {
  __shared__ float4 WP4[32][64];
  for (int i = threadIdx.x; i < 32 * 64; i += 256) {
    int k2 = i >> 6, j = i & 63;
    WP4[k2][j] = make_float4(W[(2 * k2) * 128 + j], W[(2 * k2) * 128 + j + 64],
                             W[(2 * k2 + 1) * 128 + j], W[(2 * k2 + 1) * 128 + j + 64]);
  }
  __syncthreads();
  int lane = threadIdx.x & 63;
  float a0v = att[lane], a1v = att[lane + 64];
  int gw = (blockIdx.x * 256 + threadIdx.x) >> 6;
  int nw = (gridDim.x * 256) >> 6;
  for (int n0 = 2 * gw; n0 < M; n0 += 2 * nw) {
    int nu = __builtin_amdgcn_readfirstlane(n0);
    const float* xr0 = x + nu * 64;
    const float* xr1 = x + (nu + 1) * 64;
    float a00 = 0.f, a01 = 0.f, a10 = 0.f, a11 = 0.f;
#pragma unroll 8
    for (int k2 = 0; k2 < 32; ++k2) {
      float4 wv = WP4[k2][lane];
      float xa0 = xr0[2 * k2], xa1 = xr0[2 * k2 + 1];
      float xb0 = xr1[2 * k2], xb1 = xr1[2 * k2 + 1];
      a00 += xa0 * wv.x + xa1 * wv.z;
      a01 += xa0 * wv.y + xa1 * wv.w;
      a10 += xb0 * wv.x + xb1 * wv.z;
      a11 += xb0 * wv.y + xb1 * wv.w;
    }
    float t00 = tanhf(a00) * a0v, t01 = tanhf(a01) * a1v;
    float t10 = tanhf(a10) * a0v, t11 = tanhf(a11) * a1v;
#pragma unroll
    for (int off = 32; off; off >>= 1) {
      t00 += __shfl_xor(t00, off);
      t01 += __shfl_xor(t01, off);
      t10 += __shfl_xor(t10, off);
      t11 += __shfl_xor(t11, off);
    }
    if (lane == 0) {
      ((float2*)s_out)[nu] = make_float2(t00, t01);
      ((float2*)s_out)[nu + 1] = make_float2(t10, t11);
    }
  }
}

// ================= edge weights: per CSR position (coalesced) =================
__global__ void edge_w_kernel(const int* __restrict__ csr_src, const int* __restrict__ csr_dst,
                              const int* __restrict__ csr_et, const float* __restrict__ s_h,
                              const float* __restrict__ s_t, const float* __restrict__ s_r,
                              float* __restrict__ csr_w) {
  int p = blockIdx.x * blockDim.x + threadIdx.x;
  if (p >= N_EDGE) return;
  int s = csr_src[p], d = csr_dst[p], r = csr_et[p];
  float2 a = ((const float2*)s_h)[s];
  float2 b = ((const float2*)s_t)[d];
  float2 c = ((const float2*)s_r)[r];
  float sc0 = a.x + b.x + c.x;
  float sc1 = a.y + b.y + c.y;
  sc0 = (sc0 >= 0.f) ? sc0 : 0.01f * sc0;
  sc1 = (sc1 >= 0.f) ? sc1 : 0.01f * sc1;
  ((float2*)csr_w)[p] = make_float2(expf(sc0), expf(sc1));
}

// ================= cinv: wave per node, segmented sum over contiguous csr_w =================
__global__ __launch_bounds__(256) void cinv_kernel(const int* __restrict__ rowptr,
                                                   const float* __restrict__ csr_w,
                                                   float* __restrict__ cinv) {
  int n = (blockIdx.x * 256 + threadIdx.x) >> 6;
  int lane = threadIdx.x & 63;
  if (n >= N_ENT) return;
  int p0 = rowptr[n], p1 = rowptr[n + 1];
  float z0 = 0.f, z1 = 0.f;
  for (int p = p0 + lane; p < p1; p += 64) {
    float2 w2 = ((const float2*)csr_w)[p];
    z0 += w2.x;
    z1 += w2.y;
  }
#pragma unroll
  for (int off = 32; off; off >>= 1) {
    z0 += __shfl_xor(z0, off);
    z1 += __shfl_xor(z1, off);
  }
  if (lane == 0) {
    float c0 = (p1 > p0) ? (1.0f - ALPHA) / z0 : 0.f;
    float c1 = (p1 > p0) ? (1.0f - ALPHA) / z1 : 0.f;
    ((float2*)cinv)[n] = make_float2(c0, c1);
  }
}

// ================= monolithic CSR SpMM: wave per node; 4 edge slots x 8 dims/lane =================
template <int IN_H>
__global__ __launch_bounds__(256) void spmm_kernel(
    const int* __restrict__ rowptr, const int* __restrict__ csr_dst,
    const float* __restrict__ csr_w, const float* __restrict__ cinv,
    const float* __restrict__ h, const unsigned short* __restrict__ Zin_b,
    unsigned short* __restrict__ Zout_b) {
  int lane = threadIdx.x & 63;
  int slot = lane >> 4;
  int l16 = lane & 15;
  int hh = l16 >> 3;
  int hoff = 8 * (l16 & 7);
  int gw = (blockIdx.x * 256 + threadIdx.x) >> 6;
  int nw = (gridDim.x * 256) >> 6;
  for (int n = gw; n < N_ENT; n += nw) {
    int p0 = rowptr[n], p1 = rowptr[n + 1];
    float acc[8];
#pragma unroll
    for (int j = 0; j < 8; ++j) acc[j] = 0.f;
    for (int p = p0 + slot; p < p1; p += 4) {
      int d = csr_dst[p];
      float2 w2 = ((const float2*)csr_w)[p];
      float a = hh ? w2.y : w2.x;
      uv4 q;
      if (IN_H) {
        q = *(const uv4*)(Zin_b + d * 64 + hoff);
      } else {
        q = *(const uv4*)(Zin_b + d * 128 + 8 * l16);
      }
      acc[0] += a * __uint_as_float(q.x << 16);
      acc[1] += a * __uint_as_float(q.x & 0xFFFF0000u);
      acc[2] += a * __uint_as_float(q.y << 16);
      acc[3] += a * __uint_as_float(q.y & 0xFFFF0000u);
      acc[4] += a * __uint_as_float(q.z << 16);
      acc[5] += a * __uint_as_float(q.z & 0xFFFF0000u);
      acc[6] += a * __uint_as_float(q.w << 16);
      acc[7] += a * __uint_as_float(q.w & 0xFFFF0000u);
    }
#pragma unroll
    for (int j = 0; j < 8; ++j) {
      acc[j] += __shfl_xor(acc[j], 16);
      acc[j] += __shfl_xor(acc[j], 32);
    }
    if (slot == 0) {
      float c = cinv[n * 2 + hh];
      const float* hp = h + n * 64 + hoff;
      float o[8];
#pragma unroll
      for (int j = 0; j < 8; ++j) o[j] = ALPHA * hp[j] + c * acc[j];
      uv4 qo;
      qo.x = bf16_rne(o[0]) | (bf16_rne(o[1]) << 16);
      qo.y = bf16_rne(o[2]) | (bf16_rne(o[3]) << 16);
      qo.z = bf16_rne(o[4]) | (bf16_rne(o[5]) << 16);
      qo.w = bf16_rne(o[6]) | (bf16_rne(o[7]) << 16);
      *(uv4*)(Zout_b + n * 128 + 8 * l16) = qo;
    }
  }
}

// ================= output GEMM via MFMA: [50000x128]bf16 @ [128x64]bf16 + x ==============
// Wave = 16-node tile. A-frag: lane holds Z[n0+(lane&15)][kg*8..+7], kg=lane>>4 (1 uv4/K-step).
// B-frags (Wo -> bf16) packed in LDS in fragment layout, hoisted to 64 VGPRs.
// C/D: col = lane&15 (+16*ct), row = (lane>>4)*4 + reg  [verified mapping].
__global__ __launch_bounds__(256) void out_mfma_kernel(
    const unsigned short* __restrict__ Zb, const float* __restrict__ Wo,
    const float* __restrict__ x, float* __restrict__ out) {
  __shared__ uv4 Bfrag[4][4][64];  // [col-tile][k-step][lane]
  int tid = threadIdx.x;
  for (int idx = tid; idx < 4 * 4 * 64; idx += 256) {
    int ct = idx >> 8, ks = (idx >> 6) & 3, l = idx & 63;
    int col = ct * 16 + (l & 15);
    int kbase = ks * 32 + (l >> 4) * 8;
    unsigned v[8];
#pragma unroll
    for (int j = 0; j < 8; ++j) v[j] = bf16_rne(Wo[(kbase + j) * 64 + col]);
    uv4 q;
    q.x = v[0] | (v[1] << 16);
    q.y = v[2] | (v[3] << 16);
    q.z = v[4] | (v[5] << 16);
    q.w = v[6] | (v[7] << 16);
    Bfrag[ct][ks][l] = q;
  }
  __syncthreads();
  int lane = tid & 63;
  bf16x8 B[4][4];
#pragma unroll
  for (int ct = 0; ct < 4; ++ct)
#pragma unroll
    for (int ks = 0; ks < 4; ++ks) B[ct][ks] = *(bf16x8*)&Bfrag[ct][ks][lane];

  int m = lane & 15;   // node within tile
  int kg = lane >> 4;  // k-group of 8
  int wave = (blockIdx.x * 256 + tid) >> 6;
  int nwaves = (gridDim.x * 256) >> 6;
  const int NT = N_ENT / 16;  // 3125
  for (int t = wave; t < NT; t += nwaves) {
    int n0 = t * 16;
    const unsigned short* zrow = Zb + (size_t)(n0 + m) * 128 + kg * 8;
    bf16x8 A0 = *(const bf16x8*)(zrow);
    bf16x8 A1 = *(const bf16x8*)(zrow + 32);
    bf16x8 A2 = *(const bf16x8*)(zrow + 64);
    bf16x8 A3 = *(const bf16x8*)(zrow + 96);
    f32x4 acc[4];
#pragma unroll
    for (int ct = 0; ct < 4; ++ct) {
      f32x4 a = {0.f, 0.f, 0.f, 0.f};
      a = __builtin_amdgcn_mfma_f32_16x16x32_bf16(A0, B[ct][0], a, 0, 0, 0);
      a = __builtin_amdgcn_mfma_f32_16x16x32_bf16(A1, B[ct][1], a, 0, 0, 0);
      a = __builtin_amdgcn_mfma_f32_16x16x32_bf16(A2, B[ct][2], a, 0, 0, 0);
      a = __builtin_amdgcn_mfma_f32_16x16x32_bf16(A3, B[ct][3], a, 0, 0, 0);
      acc[ct] = a;
    }
#pragma unroll
    for (int r = 0; r < 4; ++r) {
      int rr = n0 + kg * 4 + r;
#pragma unroll
      for (int ct = 0; ct < 4; ++ct) {
        int cc = ct * 16 + (lane & 15);
        out[rr * 64 + cc] = acc[ct][r] + x[rr * 64 + cc];
      }
    }
  }
}

extern "C" void kernel_launch(void* const* d_in, const int* in_sizes, int n_in,
                              void* d_out, int out_size, void* d_ws, size_t ws_size,
                              hipStream_t stream) {
  const float* ent0 = (const float*)d_in[0];
  const float* rel  = (const float*)d_in[1];
  const int* eidx   = (const int*)d_in[2];
  const int* src    = eidx;
  const int* dst    = eidx + N_EDGE;
  const int* et     = (const int*)d_in[3];
  const float* gam  = (const float*)d_in[4];
  const float* bet  = (const float*)d_in[5];
  const float* W_h  = (const float*)d_in[6];
  const float* W_t  = (const float*)d_in[7];
  const float* W_r  = (const float*)d_in[8];
  const float* att_h = (const float*)d_in[9];
  const float* att_t = (const float*)d_in[10];
  const float* att_r = (const float*)d_in[11];
  const float* W_o  = (const float*)d_in[12];
  float* outp = (float*)d_out;

  char* w = (char*)d_ws;
  auto alloc = [&](size_t bytes) {
    char* p = w;
    w += (bytes + 255) & ~(size_t)255;
    return p;
  };
  float* ent1   = (float*)alloc((size_t)N_ENT * 64 * 4);
  float* h      = (float*)alloc((size_t)N_ENT * 64 * 4);
  unsigned short* h_bf = (unsigned short*)alloc((size_t)N_ENT * 64 * 2);
  float* s_h    = (float*)alloc((size_t)N_ENT * 2 * 4);
  float* s_t    = (float*)alloc((size_t)N_ENT * 2 * 4);
  float* s_r    = (float*)alloc((size_t)N_REL * 2 * 4);
  float* cinv   = (float*)alloc((size_t)N_ENT * 2 * 4);
  float* csr_w  = (float*)alloc((size_t)N_EDGE * 2 * 4);
  unsigned short* Zb0 = (unsigned short*)alloc((size_t)N_ENT * 128 * 2);
  unsigned short* Zb1 = (unsigned short*)alloc((size_t)N_ENT * 128 * 2);
  int* deg      = (int*)alloc((size_t)N_ENT * 4);
  int* exc      = (int*)alloc((size_t)N_ENT * 4);
  int* bsum     = (int*)alloc((size_t)NBLK * 4);
  int* boff     = (int*)alloc((size_t)(NBLK + 1) * 4);
  int* rowptr   = (int*)alloc((size_t)(N_ENT + 1) * 4);
  int* cursor   = (int*)alloc((size_t)N_ENT * 4);
  int* csr_src  = (int*)alloc((size_t)N_EDGE * 4);
  int* csr_dst  = (int*)alloc((size_t)N_EDGE * 4);
  int* csr_et   = (int*)alloc((size_t)N_EDGE * 4);

  const int EB = (N_EDGE + 255) / 256;

  // ---- CSR build ----
  hipMemsetAsync(deg, 0, (size_t)N_ENT * 4, stream);
  deg_kernel<<<EB, 256, 0, stream>>>(src, deg);
  scan1_kernel<<<NBLK, 1024, 0, stream>>>(deg, exc, bsum);
  scan2_kernel<<<1, 64, 0, stream>>>(bsum, boff);
  scan3_kernel<<<NBLK, 1024, 0, stream>>>(exc, boff, rowptr);
  hipMemcpyAsync(cursor, rowptr, (size_t)N_ENT * 4, hipMemcpyDeviceToDevice, stream);
  scatter_kernel<<<EB, 256, 0, stream>>>(src, dst, et, cursor, csr_src, csr_dst, csr_et);

  for (int l = 0; l < 2; ++l) {
    const float* x = (l == 0) ? ent0 : ent1;
    float* y = (l == 0) ? ent1 : outp;

    ln_kernel<<<(N_ENT + 3) / 4, 256, 0, stream>>>(x, gam + l * 64, bet + l * 64, h, h_bf);
    scores_kernel<<<512, 256, 0, stream>>>(h, W_h + l * 8192, att_h + l * 128, s_h, N_ENT);
    scores_kernel<<<512, 256, 0, stream>>>(h, W_t + l * 8192, att_t + l * 128, s_t, N_ENT);
    scores_kernel<<<8, 256, 0, stream>>>(rel, W_r + l * 8192, att_r + l * 128, s_r, N_REL);

    edge_w_kernel<<<EB, 256, 0, stream>>>(csr_src, csr_dst, csr_et, s_h, s_t, s_r, csr_w);
    cinv_kernel<<<(N_ENT * 64 + 255) / 256, 256, 0, stream>>>(rowptr, csr_w, cinv);

    // ---- PPR power iteration: h_bf -> Zb0 -> Zb1 -> Zb0 (all bf16) ----
    spmm_kernel<1><<<2048, 256, 0, stream>>>(rowptr, csr_dst, csr_w, cinv, h, h_bf, Zb0);
    spmm_kernel<0><<<2048, 256, 0, stream>>>(rowptr, csr_dst, csr_w, cinv, h, Zb0, Zb1);
    spmm_kernel<0><<<2048, 256, 0, stream>>>(rowptr, csr_dst, csr_w, cinv, h, Zb1, Zb0);

    out_mfma_kernel<<<512, 256, 0, stream>>>(Zb0, W_o + l * 8192, x, y);
  }
}

// Round 14
// 426.795 us; speedup vs baseline: 1.3646x; 1.1728x over previous
//
#include <hip/hip_runtime.h>

#define N_ENT 50000
#define N_REL 500
#define N_EDGE 500000
#define HEADS 2
#define DIM 64
#define POW_ITER 3
#define ALPHA 0.15f
#define LN_EPS 1e-5f
#define NBLK 49  // ceil(N_ENT/1024)

typedef unsigned uv4 __attribute__((ext_vector_type(4)));
typedef short bf16x8 __attribute__((ext_vector_type(8)));
typedef float f32x4 __attribute__((ext_vector_type(4)));

// bf16 round-to-nearest-even pack
static __device__ __forceinline__ unsigned bf16_rne(float f) {
  unsigned u = __float_as_uint(f);
  return (u + 0x7FFFu + ((u >> 16) & 1u)) >> 16;
}

// ================= CSR build (once per launch; graph is layer-invariant) =================
__global__ void deg_kernel(const int* __restrict__ src, int* __restrict__ deg) {
  int e = blockIdx.x * blockDim.x + threadIdx.x;
  if (e >= N_EDGE) return;
  atomicAdd(&deg[src[e]], 1);
}

__global__ __launch_bounds__(1024) void scan1_kernel(const int* __restrict__ deg,
                                                     int* __restrict__ exc,
                                                     int* __restrict__ bsum) {
  __shared__ int tmp[1024];
  int tid = threadIdx.x;
  int i = blockIdx.x * 1024 + tid;
  int v = (i < N_ENT) ? deg[i] : 0;
  tmp[tid] = v;
  __syncthreads();
  for (int off = 1; off < 1024; off <<= 1) {
    int t = (tid >= off) ? tmp[tid - off] : 0;
    __syncthreads();
    tmp[tid] += t;
    __syncthreads();
  }
  if (i < N_ENT) exc[i] = tmp[tid] - v;
  if (tid == 1023) bsum[blockIdx.x] = tmp[1023];
}

__global__ void scan2_kernel(const int* __restrict__ bsum, int* __restrict__ boff) {
  int t = threadIdx.x;  // 64 threads
  int v = (t < NBLK) ? bsum[t] : 0;
  int incl = v;
#pragma unroll
  for (int off = 1; off < 64; off <<= 1) {
    int u = __shfl_up(incl, off);
    if (t >= off) incl += u;
  }
  if (t < NBLK) boff[t] = incl - v;
  if (t == NBLK - 1) boff[NBLK] = incl;
}

__global__ __launch_bounds__(1024) void scan3_kernel(const int* __restrict__ exc,
                                                     const int* __restrict__ boff,
                                                     int* __restrict__ rowptr) {
  int i = blockIdx.x * 1024 + threadIdx.x;
  if (i < N_ENT) rowptr[i] = exc[i] + boff[i >> 10];
  if (i == N_ENT) rowptr[N_ENT] = boff[NBLK];
}

// scatter: csr_src/csr_dst/csr_et in CSR position order
__global__ void scatter_kernel(const int* __restrict__ src, const int* __restrict__ dst,
                               const int* __restrict__ et, int* __restrict__ cursor,
                               int* __restrict__ csr_src, int* __restrict__ csr_dst,
                               int* __restrict__ csr_et) {
  int e = blockIdx.x * blockDim.x + threadIdx.x;
  if (e >= N_EDGE) return;
  int s = src[e];
  int p = atomicAdd(&cursor[s], 1);
  csr_src[p] = s;
  csr_dst[p] = dst[e];
  csr_et[p] = et[e];
}

// ================= LayerNorm: one wave per node; writes f32 h and bf16 h_bf =================
__global__ void ln_kernel(const float* __restrict__ x, const float* __restrict__ g,
                          const float* __restrict__ b, float* __restrict__ h,
                          unsigned short* __restrict__ h_bf) {
  int wid = (blockIdx.x * blockDim.x + threadIdx.x) >> 6;
  int lane = threadIdx.x & 63;
  if (wid >= N_ENT) return;
  float v = x[wid * 64 + lane];
  float s = v;
#pragma unroll
  for (int off = 32; off; off >>= 1) s += __shfl_xor(s, off);
  float mu = s * (1.0f / 64.0f);
  float d = v - mu;
  float s2 = d * d;
#pragma unroll
  for (int off = 32; off; off >>= 1) s2 += __shfl_xor(s2, off);
  float rs = rsqrtf(s2 * (1.0f / 64.0f) + LN_EPS);
  float hv = d * rs * g[lane] + b[lane];
  h[wid * 64 + lane] = hv;
  h_bf[wid * 64 + lane] = (unsigned short)bf16_rne(hv);
}

// ================= entity scores via MFMA: T = h@[W_h|W_t], s = sum tanh(T)*att ==========
// Wave = 16-node tile. A: lane holds h_bf[n0+(lane&15)][kg*8..+7], kg=lane>>4 (K=64 -> 2 frags).
// B: W (f32->bf16) fragments in LDS [mat][col-tile][k-step][lane]; col=l&15+16ct, k=ks*32+(l>>4)*8.
// C/D: col=lane&15, row=kg*4+reg (HW-verified via out_mfma). Reduce cols via shfl_xor(1,2,4,8).
__global__ __launch_bounds__(256) void scores2_mfma_kernel(
    const unsigned short* __restrict__ h_bf, const float* __restrict__ Wh,
    const float* __restrict__ Wt, const float* __restrict__ ah,
    const float* __restrict__ at, float* __restrict__ s_h, float* __restrict__ s_t) {
  __shared__ uv4 Bfrag[2][8][2][64];  // 32 KB
  int tid = threadIdx.x;
  for (int idx = tid; idx < 2 * 8 * 2 * 64; idx += 256) {
    int l = idx & 63;
    int ks = (idx >> 6) & 1;
    int ct = (idx >> 7) & 7;
    int mat = idx >> 10;
    const float* W = mat ? Wt : Wh;
    int col = ct * 16 + (l & 15);
    int kbase = ks * 32 + (l >> 4) * 8;
    unsigned v[8];
#pragma unroll
    for (int j = 0; j < 8; ++j) v[j] = bf16_rne(W[(kbase + j) * 128 + col]);
    uv4 q;
    q.x = v[0] | (v[1] << 16);
    q.y = v[2] | (v[3] << 16);
    q.z = v[4] | (v[5] << 16);
    q.w = v[6] | (v[7] << 16);
    Bfrag[mat][ct][ks][l] = q;
  }
  __syncthreads();
  int lane = tid & 63;
  int l15 = lane & 15;
  int kg = lane >> 4;
  float attv[2][8];
#pragma unroll
  for (int ct = 0; ct < 8; ++ct) {
    attv[0][ct] = ah[ct * 16 + l15];
    attv[1][ct] = at[ct * 16 + l15];
  }
  int wave = (blockIdx.x * 256 + tid) >> 6;
  int nwaves = (gridDim.x * 256) >> 6;
  const int NT = N_ENT / 16;  // 3125
  for (int t = wave; t < NT; t += nwaves) {
    int n0 = t * 16;
    const unsigned short* zrow = h_bf + (size_t)(n0 + l15) * 64 + kg * 8;
    bf16x8 A0 = *(const bf16x8*)(zrow);
    bf16x8 A1 = *(const bf16x8*)(zrow + 32);
    float ph[2][2][4];
#pragma unroll
    for (int m2 = 0; m2 < 2; ++m2)
#pragma unroll
      for (int hd = 0; hd < 2; ++hd)
#pragma unroll
        for (int r = 0; r < 4; ++r) ph[m2][hd][r] = 0.f;
#pragma unroll
    for (int mat = 0; mat < 2; ++mat) {
#pragma unroll
      for (int ct = 0; ct < 8; ++ct) {
        f32x4 a = {0.f, 0.f, 0.f, 0.f};
        a = __builtin_amdgcn_mfma_f32_16x16x32_bf16(A0, *(bf16x8*)&Bfrag[mat][ct][0][lane], a, 0, 0, 0);
        a = __builtin_amdgcn_mfma_f32_16x16x32_bf16(A1, *(bf16x8*)&Bfrag[mat][ct][1][lane], a, 0, 0, 0);
        int hd = ct >> 2;
        float av = attv[mat][ct];
#pragma unroll
        for (int r = 0; r < 4; ++r) ph[mat][hd][r] += tanhf(a[r]) * av;
      }
    }
    // reduce over the 16 lanes (l15) of each col group
#pragma unroll
    for (int mat = 0; mat < 2; ++mat)
#pragma unroll
      for (int hd = 0; hd < 2; ++hd)
#pragma unroll
        for (int r = 0; r < 4; ++r) {
          float v = ph[mat][hd][r];
          v += __shfl_xor(v, 1);
          v += __shfl_xor(v, 2);
          v += __shfl_xor(v, 4);
          v += __shfl_xor(v, 8);
          ph[mat][hd][r] = v;
        }
    if (l15 == 0) {
#pragma unroll
      for (int r = 0; r < 4; ++r) {
        int row = n0 + kg * 4 + r;
        ((float2*)s_h)[row] = make_float2(ph[0][0][r], ph[0][1][r]);
        ((float2*)s_t)[row] = make_float2(ph[1][0][r], ph[1][1][r]);
      }
    }
  }
}

// ================= relation scores (small M): W staged in LDS float4; 2 nodes/wave ============
__global__ __launch_bounds__(256) void scores_kernel(
    const float* __restrict__ x, const float* __restrict__ W,
    const float* __restrict__ att, float* __restrict__ s_out, int M) {
  __shared__ float4 WP4[32][64];
  for (int i = threadIdx.x; i < 32 * 64; i += 256) {
    int k2 = i >> 6, j = i & 63;
    WP4[k2][j] = make_float4(W[(2 * k2) * 128 + j], W[(2 * k2) * 128 + j + 64],
                             W[(2 * k2 + 1) * 128 + j], W[(2 * k2 + 1) * 128 + j + 64]);
  }
  __syncthreads();
  int lane = threadIdx.x & 63;
  float a0v = att[lane], a1v = att[lane + 64];
  int gw = (blockIdx.x * 256 + threadIdx.x) >> 6;
  int nw = (gridDim.x * 256) >> 6;
  for (int n0 = 2 * gw; n0 < M; n0 += 2 * nw) {
    int nu = __builtin_amdgcn_readfirstlane(n0);
    const float* xr0 = x + nu * 64;
    const float* xr1 = x + (nu + 1) * 64;
    float a00 = 0.f, a01 = 0.f, a10 = 0.f, a11 = 0.f;
#pragma unroll 8
    for (int k2 = 0; k2 < 32; ++k2) {
      float4 wv = WP4[k2][lane];
      float xa0 = xr0[2 * k2], xa1 = xr0[2 * k2 + 1];
      float xb0 = xr1[2 * k2], xb1 = xr1[2 * k2 + 1];
      a00 += xa0 * wv.x + xa1 * wv.z;
      a01 += xa0 * wv.y + xa1 * wv.w;
      a10 += xb0 * wv.x + xb1 * wv.z;
      a11 += xb0 * wv.y + xb1 * wv.w;
    }
    float t00 = tanhf(a00) * a0v, t01 = tanhf(a01) * a1v;
    float t10 = tanhf(a10) * a0v, t11 = tanhf(a11) * a1v;
#pragma unroll
    for (int off = 32; off; off >>= 1) {
      t00 += __shfl_xor(t00, off);
      t01 += __shfl_xor(t01, off);
      t10 += __shfl_xor(t10, off);
      t11 += __shfl_xor(t11, off);
    }
    if (lane == 0) {
      ((float2*)s_out)[nu] = make_float2(t00, t01);
      ((float2*)s_out)[nu + 1] = make_float2(t10, t11);
    }
  }
}

// ================= edge weights: per CSR position (coalesced) =================
__global__ void edge_w_kernel(const int* __restrict__ csr_src, const int* __restrict__ csr_dst,
                              const int* __restrict__ csr_et, const float* __restrict__ s_h,
                              const float* __restrict__ s_t, const float* __restrict__ s_r,
                              float* __restrict__ csr_w) {
  int p = blockIdx.x * blockDim.x + threadIdx.x;
  if (p >= N_EDGE) return;
  int s = csr_src[p], d = csr_dst[p], r = csr_et[p];
  float2 a = ((const float2*)s_h)[s];
  float2 b = ((const float2*)s_t)[d];
  float2 c = ((const float2*)s_r)[r];
  float sc0 = a.x + b.x + c.x;
  float sc1 = a.y + b.y + c.y;
  sc0 = (sc0 >= 0.f) ? sc0 : 0.01f * sc0;
  sc1 = (sc1 >= 0.f) ? sc1 : 0.01f * sc1;
  ((float2*)csr_w)[p] = make_float2(expf(sc0), expf(sc1));
}

// ================= cinv: wave per node, segmented sum over contiguous csr_w =================
__global__ __launch_bounds__(256) void cinv_kernel(const int* __restrict__ rowptr,
                                                   const float* __restrict__ csr_w,
                                                   float* __restrict__ cinv) {
  int n = (blockIdx.x * 256 + threadIdx.x) >> 6;
  int lane = threadIdx.x & 63;
  if (n >= N_ENT) return;
  int p0 = rowptr[n], p1 = rowptr[n + 1];
  float z0 = 0.f, z1 = 0.f;
  for (int p = p0 + lane; p < p1; p += 64) {
    float2 w2 = ((const float2*)csr_w)[p];
    z0 += w2.x;
    z1 += w2.y;
  }
#pragma unroll
  for (int off = 32; off; off >>= 1) {
    z0 += __shfl_xor(z0, off);
    z1 += __shfl_xor(z1, off);
  }
  if (lane == 0) {
    float c0 = (p1 > p0) ? (1.0f - ALPHA) / z0 : 0.f;
    float c1 = (p1 > p0) ? (1.0f - ALPHA) / z1 : 0.f;
    ((float2*)cinv)[n] = make_float2(c0, c1);
  }
}

// ================= monolithic CSR SpMM: wave per node; 4 edge slots x 8 dims/lane =================
template <int IN_H>
__global__ __launch_bounds__(256) void spmm_kernel(
    const int* __restrict__ rowptr, const int* __restrict__ csr_dst,
    const float* __restrict__ csr_w, const float* __restrict__ cinv,
    const float* __restrict__ h, const unsigned short* __restrict__ Zin_b,
    unsigned short* __restrict__ Zout_b) {
  int lane = threadIdx.x & 63;
  int slot = lane >> 4;
  int l16 = lane & 15;
  int hh = l16 >> 3;
  int hoff = 8 * (l16 & 7);
  int gw = (blockIdx.x * 256 + threadIdx.x) >> 6;
  int nw = (gridDim.x * 256) >> 6;
  for (int n = gw; n < N_ENT; n += nw) {
    int p0 = rowptr[n], p1 = rowptr[n + 1];
    float acc[8];
#pragma unroll
    for (int j = 0; j < 8; ++j) acc[j] = 0.f;
    for (int p = p0 + slot; p < p1; p += 4) {
      int d = csr_dst[p];
      float2 w2 = ((const float2*)csr_w)[p];
      float a = hh ? w2.y : w2.x;
      uv4 q;
      if (IN_H) {
        q = *(const uv4*)(Zin_b + d * 64 + hoff);
      } else {
        q = *(const uv4*)(Zin_b + d * 128 + 8 * l16);
      }
      acc[0] += a * __uint_as_float(q.x << 16);
      acc[1] += a * __uint_as_float(q.x & 0xFFFF0000u);
      acc[2] += a * __uint_as_float(q.y << 16);
      acc[3] += a * __uint_as_float(q.y & 0xFFFF0000u);
      acc[4] += a * __uint_as_float(q.z << 16);
      acc[5] += a * __uint_as_float(q.z & 0xFFFF0000u);
      acc[6] += a * __uint_as_float(q.w << 16);
      acc[7] += a * __uint_as_float(q.w & 0xFFFF0000u);
    }
#pragma unroll
    for (int j = 0; j < 8; ++j) {
      acc[j] += __shfl_xor(acc[j], 16);
      acc[j] += __shfl_xor(acc[j], 32);
    }
    if (slot == 0) {
      float c = cinv[n * 2 + hh];
      const float* hp = h + n * 64 + hoff;
      float o[8];
#pragma unroll
      for (int j = 0; j < 8; ++j) o[j] = ALPHA * hp[j] + c * acc[j];
      uv4 qo;
      qo.x = bf16_rne(o[0]) | (bf16_rne(o[1]) << 16);
      qo.y = bf16_rne(o[2]) | (bf16_rne(o[3]) << 16);
      qo.z = bf16_rne(o[4]) | (bf16_rne(o[5]) << 16);
      qo.w = bf16_rne(o[6]) | (bf16_rne(o[7]) << 16);
      *(uv4*)(Zout_b + n * 128 + 8 * l16) = qo;
    }
  }
}

// ================= output GEMM via MFMA: [50000x128]bf16 @ [128x64]bf16 + x ==============
__global__ __launch_bounds__(256) void out_mfma_kernel(
    const unsigned short* __restrict__ Zb, const float* __restrict__ Wo,
    const float* __restrict__ x, float* __restrict__ out) {
  __shared__ uv4 Bfrag[4][4][64];  // [col-tile][k-step][lane]
  int tid = threadIdx.x;
  for (int idx = tid; idx < 4 * 4 * 64; idx += 256) {
    int ct = idx >> 8, ks = (idx >> 6) & 3, l = idx & 63;
    int col = ct * 16 + (l & 15);
    int kbase = ks * 32 + (l >> 4) * 8;
    unsigned v[8];
#pragma unroll
    for (int j = 0; j < 8; ++j) v[j] = bf16_rne(Wo[(kbase + j) * 64 + col]);
    uv4 q;
    q.x = v[0] | (v[1] << 16);
    q.y = v[2] | (v[3] << 16);
    q.z = v[4] | (v[5] << 16);
    q.w = v[6] | (v[7] << 16);
    Bfrag[ct][ks][l] = q;
  }
  __syncthreads();
  int lane = tid & 63;
  bf16x8 B[4][4];
#pragma unroll
  for (int ct = 0; ct < 4; ++ct)
#pragma unroll
    for (int ks = 0; ks < 4; ++ks) B[ct][ks] = *(bf16x8*)&Bfrag[ct][ks][lane];

  int m = lane & 15;   // node within tile
  int kg = lane >> 4;  // k-group of 8
  int wave = (blockIdx.x * 256 + tid) >> 6;
  int nwaves = (gridDim.x * 256) >> 6;
  const int NT = N_ENT / 16;  // 3125
  for (int t = wave; t < NT; t += nwaves) {
    int n0 = t * 16;
    const unsigned short* zrow = Zb + (size_t)(n0 + m) * 128 + kg * 8;
    bf16x8 A0 = *(const bf16x8*)(zrow);
    bf16x8 A1 = *(const bf16x8*)(zrow + 32);
    bf16x8 A2 = *(const bf16x8*)(zrow + 64);
    bf16x8 A3 = *(const bf16x8*)(zrow + 96);
    f32x4 acc[4];
#pragma unroll
    for (int ct = 0; ct < 4; ++ct) {
      f32x4 a = {0.f, 0.f, 0.f, 0.f};
      a = __builtin_amdgcn_mfma_f32_16x16x32_bf16(A0, B[ct][0], a, 0, 0, 0);
      a = __builtin_amdgcn_mfma_f32_16x16x32_bf16(A1, B[ct][1], a, 0, 0, 0);
      a = __builtin_amdgcn_mfma_f32_16x16x32_bf16(A2, B[ct][2], a, 0, 0, 0);
      a = __builtin_amdgcn_mfma_f32_16x16x32_bf16(A3, B[ct][3], a, 0, 0, 0);
      acc[ct] = a;
    }
#pragma unroll
    for (int r = 0; r < 4; ++r) {
      int rr = n0 + kg * 4 + r;
#pragma unroll
      for (int ct = 0; ct < 4; ++ct) {
        int cc = ct * 16 + (lane & 15);
        out[rr * 64 + cc] = acc[ct][r] + x[rr * 64 + cc];
      }
    }
  }
}

extern "C" void kernel_launch(void* const* d_in, const int* in_sizes, int n_in,
                              void* d_out, int out_size, void* d_ws, size_t ws_size,
                              hipStream_t stream) {
  const float* ent0 = (const float*)d_in[0];
  const float* rel  = (const float*)d_in[1];
  const int* eidx   = (const int*)d_in[2];
  const int* src    = eidx;
  const int* dst    = eidx + N_EDGE;
  const int* et     = (const int*)d_in[3];
  const float* gam  = (const float*)d_in[4];
  const float* bet  = (const float*)d_in[5];
  const float* W_h  = (const float*)d_in[6];
  const float* W_t  = (const float*)d_in[7];
  const float* W_r  = (const float*)d_in[8];
  const float* att_h = (const float*)d_in[9];
  const float* att_t = (const float*)d_in[10];
  const float* att_r = (const float*)d_in[11];
  const float* W_o  = (const float*)d_in[12];
  float* outp = (float*)d_out;

  char* w = (char*)d_ws;
  auto alloc = [&](size_t bytes) {
    char* p = w;
    w += (bytes + 255) & ~(size_t)255;
    return p;
  };
  float* ent1   = (float*)alloc((size_t)N_ENT * 64 * 4);
  float* h      = (float*)alloc((size_t)N_ENT * 64 * 4);
  unsigned short* h_bf = (unsigned short*)alloc((size_t)N_ENT * 64 * 2);
  float* s_h    = (float*)alloc((size_t)N_ENT * 2 * 4);
  float* s_t    = (float*)alloc((size_t)N_ENT * 2 * 4);
  float* s_r    = (float*)alloc((size_t)N_REL * 2 * 4);
  float* cinv   = (float*)alloc((size_t)N_ENT * 2 * 4);
  float* csr_w  = (float*)alloc((size_t)N_EDGE * 2 * 4);
  unsigned short* Zb0 = (unsigned short*)alloc((size_t)N_ENT * 128 * 2);
  unsigned short* Zb1 = (unsigned short*)alloc((size_t)N_ENT * 128 * 2);
  int* deg      = (int*)alloc((size_t)N_ENT * 4);
  int* exc      = (int*)alloc((size_t)N_ENT * 4);
  int* bsum     = (int*)alloc((size_t)NBLK * 4);
  int* boff     = (int*)alloc((size_t)(NBLK + 1) * 4);
  int* rowptr   = (int*)alloc((size_t)(N_ENT + 1) * 4);
  int* cursor   = (int*)alloc((size_t)N_ENT * 4);
  int* csr_src  = (int*)alloc((size_t)N_EDGE * 4);
  int* csr_dst  = (int*)alloc((size_t)N_EDGE * 4);
  int* csr_et   = (int*)alloc((size_t)N_EDGE * 4);

  const int EB = (N_EDGE + 255) / 256;

  // ---- CSR build ----
  hipMemsetAsync(deg, 0, (size_t)N_ENT * 4, stream);
  deg_kernel<<<EB, 256, 0, stream>>>(src, deg);
  scan1_kernel<<<NBLK, 1024, 0, stream>>>(deg, exc, bsum);
  scan2_kernel<<<1, 64, 0, stream>>>(bsum, boff);
  scan3_kernel<<<NBLK, 1024, 0, stream>>>(exc, boff, rowptr);
  hipMemcpyAsync(cursor, rowptr, (size_t)N_ENT * 4, hipMemcpyDeviceToDevice, stream);
  scatter_kernel<<<EB, 256, 0, stream>>>(src, dst, et, cursor, csr_src, csr_dst, csr_et);

  for (int l = 0; l < 2; ++l) {
    const float* x = (l == 0) ? ent0 : ent1;
    float* y = (l == 0) ? ent1 : outp;

    ln_kernel<<<(N_ENT + 3) / 4, 256, 0, stream>>>(x, gam + l * 64, bet + l * 64, h, h_bf);
    scores2_mfma_kernel<<<784, 256, 0, stream>>>(h_bf, W_h + l * 8192, W_t + l * 8192,
                                                 att_h + l * 128, att_t + l * 128, s_h, s_t);
    scores_kernel<<<8, 256, 0, stream>>>(rel, W_r + l * 8192, att_r + l * 128, s_r, N_REL);

    edge_w_kernel<<<EB, 256, 0, stream>>>(csr_src, csr_dst, csr_et, s_h, s_t, s_r, csr_w);
    cinv_kernel<<<(N_ENT * 64 + 255) / 256, 256, 0, stream>>>(rowptr, csr_w, cinv);

    // ---- PPR power iteration: h_bf -> Zb0 -> Zb1 -> Zb0 (all bf16) ----
    spmm_kernel<1><<<2048, 256, 0, stream>>>(rowptr, csr_dst, csr_w, cinv, h, h_bf, Zb0);
    spmm_kernel<0><<<2048, 256, 0, stream>>>(rowptr, csr_dst, csr_w, cinv, h, Zb0, Zb1);
    spmm_kernel<0><<<2048, 256, 0, stream>>>(rowptr, csr_dst, csr_w, cinv, h, Zb1, Zb0);

    out_mfma_kernel<<<512, 256, 0, stream>>>(Zb0, W_o + l * 8192, x, y);
  }
}

// Round 15
// 417.779 us; speedup vs baseline: 1.3941x; 1.0216x over previous
//
#include <hip/hip_runtime.h>

#define N_ENT 50000
#define N_REL 500
#define N_EDGE 500000
#define HEADS 2
#define DIM 64
#define POW_ITER 3
#define ALPHA 0.15f
#define LN_EPS 1e-5f
#define NBLK 49  // ceil(N_ENT/1024)

typedef unsigned uv4 __attribute__((ext_vector_type(4)));
typedef short bf16x8 __attribute__((ext_vector_type(8)));
typedef float f32x4 __attribute__((ext_vector_type(4)));

// bf16 round-to-nearest-even pack
static __device__ __forceinline__ unsigned bf16_rne(float f) {
  unsigned u = __float_as_uint(f);
  return (u + 0x7FFFu + ((u >> 16) & 1u)) >> 16;
}

// ================= CSR build (once per launch; graph is layer-invariant) =================
__global__ void deg_kernel(const int* __restrict__ src, int* __restrict__ deg) {
  int e = blockIdx.x * blockDim.x + threadIdx.x;
  if (e >= N_EDGE) return;
  atomicAdd(&deg[src[e]], 1);
}

__global__ __launch_bounds__(1024) void scan1_kernel(const int* __restrict__ deg,
                                                     int* __restrict__ exc,
                                                     int* __restrict__ bsum) {
  __shared__ int tmp[1024];
  int tid = threadIdx.x;
  int i = blockIdx.x * 1024 + tid;
  int v = (i < N_ENT) ? deg[i] : 0;
  tmp[tid] = v;
  __syncthreads();
  for (int off = 1; off < 1024; off <<= 1) {
    int t = (tid >= off) ? tmp[tid - off] : 0;
    __syncthreads();
    tmp[tid] += t;
    __syncthreads();
  }
  if (i < N_ENT) exc[i] = tmp[tid] - v;
  if (tid == 1023) bsum[blockIdx.x] = tmp[1023];
}

__global__ void scan2_kernel(const int* __restrict__ bsum, int* __restrict__ boff) {
  int t = threadIdx.x;  // 64 threads
  int v = (t < NBLK) ? bsum[t] : 0;
  int incl = v;
#pragma unroll
  for (int off = 1; off < 64; off <<= 1) {
    int u = __shfl_up(incl, off);
    if (t >= off) incl += u;
  }
  if (t < NBLK) boff[t] = incl - v;
  if (t == NBLK - 1) boff[NBLK] = incl;
}

__global__ __launch_bounds__(1024) void scan3_kernel(const int* __restrict__ exc,
                                                     const int* __restrict__ boff,
                                                     int* __restrict__ rowptr) {
  int i = blockIdx.x * 1024 + threadIdx.x;
  if (i < N_ENT) rowptr[i] = exc[i] + boff[i >> 10];
  if (i == N_ENT) rowptr[N_ENT] = boff[NBLK];
}

// scatter: csr_de[p] = dst | (et<<16)  (single scattered 4B write per edge)
__global__ void scatter_kernel(const int* __restrict__ src, const int* __restrict__ dst,
                               const int* __restrict__ et, int* __restrict__ cursor,
                               unsigned* __restrict__ csr_de) {
  int e = blockIdx.x * blockDim.x + threadIdx.x;
  if (e >= N_EDGE) return;
  int s = src[e];
  int p = atomicAdd(&cursor[s], 1);
  csr_de[p] = (unsigned)dst[e] | ((unsigned)et[e] << 16);
}

// ================= LayerNorm: one wave per node; writes f32 h and bf16 h_bf =================
__global__ void ln_kernel(const float* __restrict__ x, const float* __restrict__ g,
                          const float* __restrict__ b, float* __restrict__ h,
                          unsigned short* __restrict__ h_bf) {
  int wid = (blockIdx.x * blockDim.x + threadIdx.x) >> 6;
  int lane = threadIdx.x & 63;
  if (wid >= N_ENT) return;
  float v = x[wid * 64 + lane];
  float s = v;
#pragma unroll
  for (int off = 32; off; off >>= 1) s += __shfl_xor(s, off);
  float mu = s * (1.0f / 64.0f);
  float d = v - mu;
  float s2 = d * d;
#pragma unroll
  for (int off = 32; off; off >>= 1) s2 += __shfl_xor(s2, off);
  float rs = rsqrtf(s2 * (1.0f / 64.0f) + LN_EPS);
  float hv = d * rs * g[lane] + b[lane];
  h[wid * 64 + lane] = hv;
  h_bf[wid * 64 + lane] = (unsigned short)bf16_rne(hv);
}

// ================= entity scores via MFMA: T = h@[W_h|W_t], s = sum tanh(T)*att ==========
__global__ __launch_bounds__(256) void scores2_mfma_kernel(
    const unsigned short* __restrict__ h_bf, const float* __restrict__ Wh,
    const float* __restrict__ Wt, const float* __restrict__ ah,
    const float* __restrict__ at, float* __restrict__ s_h, float* __restrict__ s_t) {
  __shared__ uv4 Bfrag[2][8][2][64];  // 32 KB
  int tid = threadIdx.x;
  for (int idx = tid; idx < 2 * 8 * 2 * 64; idx += 256) {
    int l = idx & 63;
    int ks = (idx >> 6) & 1;
    int ct = (idx >> 7) & 7;
    int mat = idx >> 10;
    const float* W = mat ? Wt : Wh;
    int col = ct * 16 + (l & 15);
    int kbase = ks * 32 + (l >> 4) * 8;
    unsigned v[8];
#pragma unroll
    for (int j = 0; j < 8; ++j) v[j] = bf16_rne(W[(kbase + j) * 128 + col]);
    uv4 q;
    q.x = v[0] | (v[1] << 16);
    q.y = v[2] | (v[3] << 16);
    q.z = v[4] | (v[5] << 16);
    q.w = v[6] | (v[7] << 16);
    Bfrag[mat][ct][ks][l] = q;
  }
  __syncthreads();
  int lane = tid & 63;
  int l15 = lane & 15;
  int kg = lane >> 4;
  float attv[2][8];
#pragma unroll
  for (int ct = 0; ct < 8; ++ct) {
    attv[0][ct] = ah[ct * 16 + l15];
    attv[1][ct] = at[ct * 16 + l15];
  }
  int wave = (blockIdx.x * 256 + tid) >> 6;
  int nwaves = (gridDim.x * 256) >> 6;
  const int NT = N_ENT / 16;  // 3125
  for (int t = wave; t < NT; t += nwaves) {
    int n0 = t * 16;
    const unsigned short* zrow = h_bf + (size_t)(n0 + l15) * 64 + kg * 8;
    bf16x8 A0 = *(const bf16x8*)(zrow);
    bf16x8 A1 = *(const bf16x8*)(zrow + 32);
    float ph[2][2][4];
#pragma unroll
    for (int m2 = 0; m2 < 2; ++m2)
#pragma unroll
      for (int hd = 0; hd < 2; ++hd)
#pragma unroll
        for (int r = 0; r < 4; ++r) ph[m2][hd][r] = 0.f;
#pragma unroll
    for (int mat = 0; mat < 2; ++mat) {
#pragma unroll
      for (int ct = 0; ct < 8; ++ct) {
        f32x4 a = {0.f, 0.f, 0.f, 0.f};
        a = __builtin_amdgcn_mfma_f32_16x16x32_bf16(A0, *(bf16x8*)&Bfrag[mat][ct][0][lane], a, 0, 0, 0);
        a = __builtin_amdgcn_mfma_f32_16x16x32_bf16(A1, *(bf16x8*)&Bfrag[mat][ct][1][lane], a, 0, 0, 0);
        int hd = ct >> 2;
        float av = attv[mat][ct];
#pragma unroll
        for (int r = 0; r < 4; ++r) ph[mat][hd][r] += tanhf(a[r]) * av;
      }
    }
#pragma unroll
    for (int mat = 0; mat < 2; ++mat)
#pragma unroll
      for (int hd = 0; hd < 2; ++hd)
#pragma unroll
        for (int r = 0; r < 4; ++r) {
          float v = ph[mat][hd][r];
          v += __shfl_xor(v, 1);
          v += __shfl_xor(v, 2);
          v += __shfl_xor(v, 4);
          v += __shfl_xor(v, 8);
          ph[mat][hd][r] = v;
        }
    if (l15 == 0) {
#pragma unroll
      for (int r = 0; r < 4; ++r) {
        int row = n0 + kg * 4 + r;
        ((float2*)s_h)[row] = make_float2(ph[0][0][r], ph[0][1][r]);
        ((float2*)s_t)[row] = make_float2(ph[1][0][r], ph[1][1][r]);
      }
    }
  }
}

// ================= relation scores (small M): W staged in LDS float4; 2 nodes/wave ============
__global__ __launch_bounds__(256) void scores_kernel(
    const float* __restrict__ x, const float* __restrict__ W,
    const float* __restrict__ att, float* __restrict__ s_out, int M) {
  __shared__ float4 WP4[32][64];
  for (int i = threadIdx.x; i < 32 * 64; i += 256) {
    int k2 = i >> 6, j = i & 63;
    WP4[k2][j] = make_float4(W[(2 * k2) * 128 + j], W[(2 * k2) * 128 + j + 64],
                             W[(2 * k2 + 1) * 128 + j], W[(2 * k2 + 1) * 128 + j + 64]);
  }
  __syncthreads();
  int lane = threadIdx.x & 63;
  float a0v = att[lane], a1v = att[lane + 64];
  int gw = (blockIdx.x * 256 + threadIdx.x) >> 6;
  int nw = (gridDim.x * 256) >> 6;
  for (int n0 = 2 * gw; n0 < M; n0 += 2 * nw) {
    int nu = __builtin_amdgcn_readfirstlane(n0);
    const float* xr0 = x + nu * 64;
    const float* xr1 = x + (nu + 1) * 64;
    float a00 = 0.f, a01 = 0.f, a10 = 0.f, a11 = 0.f;
#pragma unroll 8
    for (int k2 = 0; k2 < 32; ++k2) {
      float4 wv = WP4[k2][lane];
      float xa0 = xr0[2 * k2], xa1 = xr0[2 * k2 + 1];
      float xb0 = xr1[2 * k2], xb1 = xr1[2 * k2 + 1];
      a00 += xa0 * wv.x + xa1 * wv.z;
      a01 += xa0 * wv.y + xa1 * wv.w;
      a10 += xb0 * wv.x + xb1 * wv.z;
      a11 += xb0 * wv.y + xb1 * wv.w;
    }
    float t00 = tanhf(a00) * a0v, t01 = tanhf(a01) * a1v;
    float t10 = tanhf(a10) * a0v, t11 = tanhf(a11) * a1v;
#pragma unroll
    for (int off = 32; off; off >>= 1) {
      t00 += __shfl_xor(t00, off);
      t01 += __shfl_xor(t01, off);
      t10 += __shfl_xor(t10, off);
      t11 += __shfl_xor(t11, off);
    }
    if (lane == 0) {
      ((float2*)s_out)[nu] = make_float2(t00, t01);
      ((float2*)s_out)[nu + 1] = make_float2(t10, t11);
    }
  }
}

// ================= fused edge weights + cinv: wave per node over contiguous csr_de ===========
// s_h[n] is wave-uniform; lanes stride the node's edge range; store csr_w, reduce z, write cinv.
__global__ __launch_bounds__(256) void edge_cinv_kernel(
    const int* __restrict__ rowptr, const unsigned* __restrict__ csr_de,
    const float* __restrict__ s_h, const float* __restrict__ s_t,
    const float* __restrict__ s_r, float* __restrict__ csr_w, float* __restrict__ cinv) {
  int n = (blockIdx.x * 256 + threadIdx.x) >> 6;
  int lane = threadIdx.x & 63;
  if (n >= N_ENT) return;
  int p0 = rowptr[n], p1 = rowptr[n + 1];
  float2 sh = ((const float2*)s_h)[n];
  float z0 = 0.f, z1 = 0.f;
  for (int p = p0 + lane; p < p1; p += 64) {
    unsigned de = csr_de[p];
    int d = de & 0xFFFF;
    int r = de >> 16;
    float2 st = ((const float2*)s_t)[d];
    float2 sr = ((const float2*)s_r)[r];
    float sc0 = sh.x + st.x + sr.x;
    float sc1 = sh.y + st.y + sr.y;
    sc0 = (sc0 >= 0.f) ? sc0 : 0.01f * sc0;
    sc1 = (sc1 >= 0.f) ? sc1 : 0.01f * sc1;
    float w0 = expf(sc0), w1 = expf(sc1);
    ((float2*)csr_w)[p] = make_float2(w0, w1);
    z0 += w0;
    z1 += w1;
  }
#pragma unroll
  for (int off = 32; off; off >>= 1) {
    z0 += __shfl_xor(z0, off);
    z1 += __shfl_xor(z1, off);
  }
  if (lane == 0) {
    float c0 = (p1 > p0) ? (1.0f - ALPHA) / z0 : 0.f;
    float c1 = (p1 > p0) ? (1.0f - ALPHA) / z1 : 0.f;
    ((float2*)cinv)[n] = make_float2(c0, c1);
  }
}

// ================= monolithic CSR SpMM: wave per node; 4 edge slots x 8 dims/lane =================
template <int IN_H>
__global__ __launch_bounds__(256) void spmm_kernel(
    const int* __restrict__ rowptr, const unsigned* __restrict__ csr_de,
    const float* __restrict__ csr_w, const float* __restrict__ cinv,
    const float* __restrict__ h, const unsigned short* __restrict__ Zin_b,
    unsigned short* __restrict__ Zout_b) {
  int lane = threadIdx.x & 63;
  int slot = lane >> 4;
  int l16 = lane & 15;
  int hh = l16 >> 3;
  int hoff = 8 * (l16 & 7);
  int gw = (blockIdx.x * 256 + threadIdx.x) >> 6;
  int nw = (gridDim.x * 256) >> 6;
  for (int n = gw; n < N_ENT; n += nw) {
    int p0 = rowptr[n], p1 = rowptr[n + 1];
    float acc[8];
#pragma unroll
    for (int j = 0; j < 8; ++j) acc[j] = 0.f;
    for (int p = p0 + slot; p < p1; p += 4) {
      int d = csr_de[p] & 0xFFFF;
      float2 w2 = ((const float2*)csr_w)[p];
      float a = hh ? w2.y : w2.x;
      uv4 q;
      if (IN_H) {
        q = *(const uv4*)(Zin_b + d * 64 + hoff);
      } else {
        q = *(const uv4*)(Zin_b + d * 128 + 8 * l16);
      }
      acc[0] += a * __uint_as_float(q.x << 16);
      acc[1] += a * __uint_as_float(q.x & 0xFFFF0000u);
      acc[2] += a * __uint_as_float(q.y << 16);
      acc[3] += a * __uint_as_float(q.y & 0xFFFF0000u);
      acc[4] += a * __uint_as_float(q.z << 16);
      acc[5] += a * __uint_as_float(q.z & 0xFFFF0000u);
      acc[6] += a * __uint_as_float(q.w << 16);
      acc[7] += a * __uint_as_float(q.w & 0xFFFF0000u);
    }
#pragma unroll
    for (int j = 0; j < 8; ++j) {
      acc[j] += __shfl_xor(acc[j], 16);
      acc[j] += __shfl_xor(acc[j], 32);
    }
    if (slot == 0) {
      float c = cinv[n * 2 + hh];
      const float* hp = h + n * 64 + hoff;
      float o[8];
#pragma unroll
      for (int j = 0; j < 8; ++j) o[j] = ALPHA * hp[j] + c * acc[j];
      uv4 qo;
      qo.x = bf16_rne(o[0]) | (bf16_rne(o[1]) << 16);
      qo.y = bf16_rne(o[2]) | (bf16_rne(o[3]) << 16);
      qo.z = bf16_rne(o[4]) | (bf16_rne(o[5]) << 16);
      qo.w = bf16_rne(o[6]) | (bf16_rne(o[7]) << 16);
      *(uv4*)(Zout_b + n * 128 + 8 * l16) = qo;
    }
  }
}

// ================= output GEMM via MFMA: [50000x128]bf16 @ [128x64]bf16 + x ==============
__global__ __launch_bounds__(256) void out_mfma_kernel(
    const unsigned short* __restrict__ Zb, const float* __restrict__ Wo,
    const float* __restrict__ x, float* __restrict__ out) {
  __shared__ uv4 Bfrag[4][4][64];  // [col-tile][k-step][lane]
  int tid = threadIdx.x;
  for (int idx = tid; idx < 4 * 4 * 64; idx += 256) {
    int ct = idx >> 8, ks = (idx >> 6) & 3, l = idx & 63;
    int col = ct * 16 + (l & 15);
    int kbase = ks * 32 + (l >> 4) * 8;
    unsigned v[8];
#pragma unroll
    for (int j = 0; j < 8; ++j) v[j] = bf16_rne(Wo[(kbase + j) * 64 + col]);
    uv4 q;
    q.x = v[0] | (v[1] << 16);
    q.y = v[2] | (v[3] << 16);
    q.z = v[4] | (v[5] << 16);
    q.w = v[6] | (v[7] << 16);
    Bfrag[ct][ks][l] = q;
  }
  __syncthreads();
  int lane = tid & 63;
  bf16x8 B[4][4];
#pragma unroll
  for (int ct = 0; ct < 4; ++ct)
#pragma unroll
    for (int ks = 0; ks < 4; ++ks) B[ct][ks] = *(bf16x8*)&Bfrag[ct][ks][lane];

  int m = lane & 15;   // node within tile
  int kg = lane >> 4;  // k-group of 8
  int wave = (blockIdx.x * 256 + tid) >> 6;
  int nwaves = (gridDim.x * 256) >> 6;
  const int NT = N_ENT / 16;  // 3125
  for (int t = wave; t < NT; t += nwaves) {
    int n0 = t * 16;
    const unsigned short* zrow = Zb + (size_t)(n0 + m) * 128 + kg * 8;
    bf16x8 A0 = *(const bf16x8*)(zrow);
    bf16x8 A1 = *(const bf16x8*)(zrow + 32);
    bf16x8 A2 = *(const bf16x8*)(zrow + 64);
    bf16x8 A3 = *(const bf16x8*)(zrow + 96);
    f32x4 acc[4];
#pragma unroll
    for (int ct = 0; ct < 4; ++ct) {
      f32x4 a = {0.f, 0.f, 0.f, 0.f};
      a = __builtin_amdgcn_mfma_f32_16x16x32_bf16(A0, B[ct][0], a, 0, 0, 0);
      a = __builtin_amdgcn_mfma_f32_16x16x32_bf16(A1, B[ct][1], a, 0, 0, 0);
      a = __builtin_amdgcn_mfma_f32_16x16x32_bf16(A2, B[ct][2], a, 0, 0, 0);
      a = __builtin_amdgcn_mfma_f32_16x16x32_bf16(A3, B[ct][3], a, 0, 0, 0);
      acc[ct] = a;
    }
#pragma unroll
    for (int r = 0; r < 4; ++r) {
      int rr = n0 + kg * 4 + r;
#pragma unroll
      for (int ct = 0; ct < 4; ++ct) {
        int cc = ct * 16 + (lane & 15);
        out[rr * 64 + cc] = acc[ct][r] + x[rr * 64 + cc];
      }
    }
  }
}

extern "C" void kernel_launch(void* const* d_in, const int* in_sizes, int n_in,
                              void* d_out, int out_size, void* d_ws, size_t ws_size,
                              hipStream_t stream) {
  const float* ent0 = (const float*)d_in[0];
  const float* rel  = (const float*)d_in[1];
  const int* eidx   = (const int*)d_in[2];
  const int* src    = eidx;
  const int* dst    = eidx + N_EDGE;
  const int* et     = (const int*)d_in[3];
  const float* gam  = (const float*)d_in[4];
  const float* bet  = (const float*)d_in[5];
  const float* W_h  = (const float*)d_in[6];
  const float* W_t  = (const float*)d_in[7];
  const float* W_r  = (const float*)d_in[8];
  const float* att_h = (const float*)d_in[9];
  const float* att_t = (const float*)d_in[10];
  const float* att_r = (const float*)d_in[11];
  const float* W_o  = (const float*)d_in[12];
  float* outp = (float*)d_out;

  char* w = (char*)d_ws;
  auto alloc = [&](size_t bytes) {
    char* p = w;
    w += (bytes + 255) & ~(size_t)255;
    return p;
  };
  float* ent1   = (float*)alloc((size_t)N_ENT * 64 * 4);
  float* h      = (float*)alloc((size_t)N_ENT * 64 * 4);
  unsigned short* h_bf = (unsigned short*)alloc((size_t)N_ENT * 64 * 2);
  float* s_h    = (float*)alloc((size_t)N_ENT * 2 * 4);
  float* s_t    = (float*)alloc((size_t)N_ENT * 2 * 4);
  float* s_r    = (float*)alloc((size_t)N_REL * 2 * 4);
  float* cinv   = (float*)alloc((size_t)N_ENT * 2 * 4);
  float* csr_w  = (float*)alloc((size_t)N_EDGE * 2 * 4);
  unsigned short* Zb0 = (unsigned short*)alloc((size_t)N_ENT * 128 * 2);
  unsigned short* Zb1 = (unsigned short*)alloc((size_t)N_ENT * 128 * 2);
  int* deg      = (int*)alloc((size_t)N_ENT * 4);
  int* exc      = (int*)alloc((size_t)N_ENT * 4);
  int* bsum     = (int*)alloc((size_t)NBLK * 4);
  int* boff     = (int*)alloc((size_t)(NBLK + 1) * 4);
  int* rowptr   = (int*)alloc((size_t)(N_ENT + 1) * 4);
  int* cursor   = (int*)alloc((size_t)N_ENT * 4);
  unsigned* csr_de = (unsigned*)alloc((size_t)N_EDGE * 4);

  const int EB = (N_EDGE + 255) / 256;

  // ---- CSR build ----
  hipMemsetAsync(deg, 0, (size_t)N_ENT * 4, stream);
  deg_kernel<<<EB, 256, 0, stream>>>(src, deg);
  scan1_kernel<<<NBLK, 1024, 0, stream>>>(deg, exc, bsum);
  scan2_kernel<<<1, 64, 0, stream>>>(bsum, boff);
  scan3_kernel<<<NBLK, 1024, 0, stream>>>(exc, boff, rowptr);
  hipMemcpyAsync(cursor, rowptr, (size_t)N_ENT * 4, hipMemcpyDeviceToDevice, stream);
  scatter_kernel<<<EB, 256, 0, stream>>>(src, dst, et, cursor, csr_de);

  for (int l = 0; l < 2; ++l) {
    const float* x = (l == 0) ? ent0 : ent1;
    float* y = (l == 0) ? ent1 : outp;

    ln_kernel<<<(N_ENT + 3) / 4, 256, 0, stream>>>(x, gam + l * 64, bet + l * 64, h, h_bf);
    scores2_mfma_kernel<<<192, 256, 0, stream>>>(h_bf, W_h + l * 8192, W_t + l * 8192,
                                                 att_h + l * 128, att_t + l * 128, s_h, s_t);
    scores_kernel<<<8, 256, 0, stream>>>(rel, W_r + l * 8192, att_r + l * 128, s_r, N_REL);

    edge_cinv_kernel<<<(N_ENT + 3) / 4, 256, 0, stream>>>(rowptr, csr_de, s_h, s_t, s_r,
                                                          csr_w, cinv);

    // ---- PPR power iteration: h_bf -> Zb0 -> Zb1 -> Zb0 (all bf16) ----
    spmm_kernel<1><<<2048, 256, 0, stream>>>(rowptr, csr_de, csr_w, cinv, h, h_bf, Zb0);
    spmm_kernel<0><<<2048, 256, 0, stream>>>(rowptr, csr_de, csr_w, cinv, h, Zb0, Zb1);
    spmm_kernel<0><<<2048, 256, 0, stream>>>(rowptr, csr_de, csr_w, cinv, h, Zb1, Zb0);

    out_mfma_kernel<<<160, 256, 0, stream>>>(Zb0, W_o + l * 8192, x, y);
  }
}

// Round 16
// 361.889 us; speedup vs baseline: 1.6094x; 1.1544x over previous
//
#include <hip/hip_runtime.h>

#define N_ENT 50000
#define N_REL 500
#define N_EDGE 500000
#define HEADS 2
#define DIM 64
#define POW_ITER 3
#define ALPHA 0.15f
#define LN_EPS 1e-5f
#define NBLK 49  // ceil(N_ENT/1024)

typedef unsigned uv4 __attribute__((ext_vector_type(4)));
typedef short bf16x8 __attribute__((ext_vector_type(8)));
typedef float f32x4 __attribute__((ext_vector_type(4)));

// bf16 round-to-nearest-even pack
static __device__ __forceinline__ unsigned bf16_rne(float f) {
  unsigned u = __float_as_uint(f);
  return (u + 0x7FFFu + ((u >> 16) & 1u)) >> 16;
}

// branch-free tanh: (e^2x-1)/(e^2x+1), clamped so exp stays finite
static __device__ __forceinline__ float fast_tanh(float x) {
  float xc = fminf(fmaxf(x, -10.f), 10.f);
  float t = __expf(2.f * xc);
  return (t - 1.f) * __builtin_amdgcn_rcpf(t + 1.f);
}

// ================= CSR build (once per launch; graph is layer-invariant) =================
__global__ void deg_kernel(const int* __restrict__ src, int* __restrict__ deg) {
  int e = blockIdx.x * blockDim.x + threadIdx.x;
  if (e >= N_EDGE) return;
  atomicAdd(&deg[src[e]], 1);
}

__global__ __launch_bounds__(1024) void scan1_kernel(const int* __restrict__ deg,
                                                     int* __restrict__ exc,
                                                     int* __restrict__ bsum) {
  __shared__ int tmp[1024];
  int tid = threadIdx.x;
  int i = blockIdx.x * 1024 + tid;
  int v = (i < N_ENT) ? deg[i] : 0;
  tmp[tid] = v;
  __syncthreads();
  for (int off = 1; off < 1024; off <<= 1) {
    int t = (tid >= off) ? tmp[tid - off] : 0;
    __syncthreads();
    tmp[tid] += t;
    __syncthreads();
  }
  if (i < N_ENT) exc[i] = tmp[tid] - v;
  if (tid == 1023) bsum[blockIdx.x] = tmp[1023];
}

__global__ void scan2_kernel(const int* __restrict__ bsum, int* __restrict__ boff) {
  int t = threadIdx.x;  // 64 threads
  int v = (t < NBLK) ? bsum[t] : 0;
  int incl = v;
#pragma unroll
  for (int off = 1; off < 64; off <<= 1) {
    int u = __shfl_up(incl, off);
    if (t >= off) incl += u;
  }
  if (t < NBLK) boff[t] = incl - v;
  if (t == NBLK - 1) boff[NBLK] = incl;
}

__global__ __launch_bounds__(1024) void scan3_kernel(const int* __restrict__ exc,
                                                     const int* __restrict__ boff,
                                                     int* __restrict__ rowptr) {
  int i = blockIdx.x * 1024 + threadIdx.x;
  if (i < N_ENT) rowptr[i] = exc[i] + boff[i >> 10];
  if (i == N_ENT) rowptr[N_ENT] = boff[NBLK];
}

// scatter: csr_de[p] = dst | (et<<16)  (single scattered 4B write per edge)
__global__ void scatter_kernel(const int* __restrict__ src, const int* __restrict__ dst,
                               const int* __restrict__ et, int* __restrict__ cursor,
                               unsigned* __restrict__ csr_de) {
  int e = blockIdx.x * blockDim.x + threadIdx.x;
  if (e >= N_EDGE) return;
  int s = src[e];
  int p = atomicAdd(&cursor[s], 1);
  csr_de[p] = (unsigned)dst[e] | ((unsigned)et[e] << 16);
}

// ================= LayerNorm: one wave per node; writes f32 h and bf16 h_bf =================
__global__ void ln_kernel(const float* __restrict__ x, const float* __restrict__ g,
                          const float* __restrict__ b, float* __restrict__ h,
                          unsigned short* __restrict__ h_bf) {
  int wid = (blockIdx.x * blockDim.x + threadIdx.x) >> 6;
  int lane = threadIdx.x & 63;
  if (wid >= N_ENT) return;
  float v = x[wid * 64 + lane];
  float s = v;
#pragma unroll
  for (int off = 32; off; off >>= 1) s += __shfl_xor(s, off);
  float mu = s * (1.0f / 64.0f);
  float d = v - mu;
  float s2 = d * d;
#pragma unroll
  for (int off = 32; off; off >>= 1) s2 += __shfl_xor(s2, off);
  float rs = rsqrtf(s2 * (1.0f / 64.0f) + LN_EPS);
  float hv = d * rs * g[lane] + b[lane];
  h[wid * 64 + lane] = hv;
  h_bf[wid * 64 + lane] = (unsigned short)bf16_rne(hv);
}

// ================= entity scores via MFMA: T = h@[W_h|W_t], s = sum tanh(T)*att ==========
__global__ __launch_bounds__(256) void scores2_mfma_kernel(
    const unsigned short* __restrict__ h_bf, const float* __restrict__ Wh,
    const float* __restrict__ Wt, const float* __restrict__ ah,
    const float* __restrict__ at, float* __restrict__ s_h, float* __restrict__ s_t) {
  __shared__ uv4 Bfrag[2][8][2][64];  // 32 KB
  int tid = threadIdx.x;
  for (int idx = tid; idx < 2 * 8 * 2 * 64; idx += 256) {
    int l = idx & 63;
    int ks = (idx >> 6) & 1;
    int ct = (idx >> 7) & 7;
    int mat = idx >> 10;
    const float* W = mat ? Wt : Wh;
    int col = ct * 16 + (l & 15);
    int kbase = ks * 32 + (l >> 4) * 8;
    unsigned v[8];
#pragma unroll
    for (int j = 0; j < 8; ++j) v[j] = bf16_rne(W[(kbase + j) * 128 + col]);
    uv4 q;
    q.x = v[0] | (v[1] << 16);
    q.y = v[2] | (v[3] << 16);
    q.z = v[4] | (v[5] << 16);
    q.w = v[6] | (v[7] << 16);
    Bfrag[mat][ct][ks][l] = q;
  }
  __syncthreads();
  int lane = tid & 63;
  int l15 = lane & 15;
  int kg = lane >> 4;
  float attv[2][8];
#pragma unroll
  for (int ct = 0; ct < 8; ++ct) {
    attv[0][ct] = ah[ct * 16 + l15];
    attv[1][ct] = at[ct * 16 + l15];
  }
  int wave = (blockIdx.x * 256 + tid) >> 6;
  int nwaves = (gridDim.x * 256) >> 6;
  const int NT = N_ENT / 16;  // 3125
  for (int t = wave; t < NT; t += nwaves) {
    int n0 = t * 16;
    const unsigned short* zrow = h_bf + (size_t)(n0 + l15) * 64 + kg * 8;
    bf16x8 A0 = *(const bf16x8*)(zrow);
    bf16x8 A1 = *(const bf16x8*)(zrow + 32);
    float ph[2][2][4];
#pragma unroll
    for (int m2 = 0; m2 < 2; ++m2)
#pragma unroll
      for (int hd = 0; hd < 2; ++hd)
#pragma unroll
        for (int r = 0; r < 4; ++r) ph[m2][hd][r] = 0.f;
#pragma unroll
    for (int mat = 0; mat < 2; ++mat) {
#pragma unroll
      for (int ct = 0; ct < 8; ++ct) {
        f32x4 a = {0.f, 0.f, 0.f, 0.f};
        a = __builtin_amdgcn_mfma_f32_16x16x32_bf16(A0, *(bf16x8*)&Bfrag[mat][ct][0][lane], a, 0, 0, 0);
        a = __builtin_amdgcn_mfma_f32_16x16x32_bf16(A1, *(bf16x8*)&Bfrag[mat][ct][1][lane], a, 0, 0, 0);
        int hd = ct >> 2;
        float av = attv[mat][ct];
#pragma unroll
        for (int r = 0; r < 4; ++r) ph[mat][hd][r] += fast_tanh(a[r]) * av;
      }
    }
#pragma unroll
    for (int mat = 0; mat < 2; ++mat)
#pragma unroll
      for (int hd = 0; hd < 2; ++hd)
#pragma unroll
        for (int r = 0; r < 4; ++r) {
          float v = ph[mat][hd][r];
          v += __shfl_xor(v, 1);
          v += __shfl_xor(v, 2);
          v += __shfl_xor(v, 4);
          v += __shfl_xor(v, 8);
          ph[mat][hd][r] = v;
        }
    if (l15 == 0) {
#pragma unroll
      for (int r = 0; r < 4; ++r) {
        int row = n0 + kg * 4 + r;
        ((float2*)s_h)[row] = make_float2(ph[0][0][r], ph[0][1][r]);
        ((float2*)s_t)[row] = make_float2(ph[1][0][r], ph[1][1][r]);
      }
    }
  }
}

// ================= relation scores (small M): W staged in LDS float4; 2 nodes/wave ============
__global__ __launch_bounds__(256) void scores_kernel(
    const float* __restrict__ x, const float* __restrict__ W,
    const float* __restrict__ att, float* __restrict__ s_out, int M) {
  __shared__ float4 WP4[32][64];
  for (int i = threadIdx.x; i < 32 * 64; i += 256) {
    int k2 = i >> 6, j = i & 63;
    WP4[k2][j] = make_float4(W[(2 * k2) * 128 + j], W[(2 * k2) * 128 + j + 64],
                             W[(2 * k2 + 1) * 128 + j], W[(2 * k2 + 1) * 128 + j + 64]);
  }
  __syncthreads();
  int lane = threadIdx.x & 63;
  float a0v = att[lane], a1v = att[lane + 64];
  int gw = (blockIdx.x * 256 + threadIdx.x) >> 6;
  int nw = (gridDim.x * 256) >> 6;
  for (int n0 = 2 * gw; n0 < M; n0 += 2 * nw) {
    int nu = __builtin_amdgcn_readfirstlane(n0);
    const float* xr0 = x + nu * 64;
    const float* xr1 = x + (nu + 1) * 64;
    float a00 = 0.f, a01 = 0.f, a10 = 0.f, a11 = 0.f;
#pragma unroll 8
    for (int k2 = 0; k2 < 32; ++k2) {
      float4 wv = WP4[k2][lane];
      float xa0 = xr0[2 * k2], xa1 = xr0[2 * k2 + 1];
      float xb0 = xr1[2 * k2], xb1 = xr1[2 * k2 + 1];
      a00 += xa0 * wv.x + xa1 * wv.z;
      a01 += xa0 * wv.y + xa1 * wv.w;
      a10 += xb0 * wv.x + xb1 * wv.z;
      a11 += xb0 * wv.y + xb1 * wv.w;
    }
    float t00 = fast_tanh(a00) * a0v, t01 = fast_tanh(a01) * a1v;
    float t10 = fast_tanh(a10) * a0v, t11 = fast_tanh(a11) * a1v;
#pragma unroll
    for (int off = 32; off; off >>= 1) {
      t00 += __shfl_xor(t00, off);
      t01 += __shfl_xor(t01, off);
      t10 += __shfl_xor(t10, off);
      t11 += __shfl_xor(t11, off);
    }
    if (lane == 0) {
      ((float2*)s_out)[nu] = make_float2(t00, t01);
      ((float2*)s_out)[nu + 1] = make_float2(t10, t11);
    }
  }
}

// ================= fused edge weights + cinv: wave per node over contiguous csr_de ===========
__global__ __launch_bounds__(256) void edge_cinv_kernel(
    const int* __restrict__ rowptr, const unsigned* __restrict__ csr_de,
    const float* __restrict__ s_h, const float* __restrict__ s_t,
    const float* __restrict__ s_r, float* __restrict__ csr_w, float* __restrict__ cinv) {
  int n = (blockIdx.x * 256 + threadIdx.x) >> 6;
  int lane = threadIdx.x & 63;
  if (n >= N_ENT) return;
  int p0 = rowptr[n], p1 = rowptr[n + 1];
  float2 sh = ((const float2*)s_h)[n];
  float z0 = 0.f, z1 = 0.f;
  for (int p = p0 + lane; p < p1; p += 64) {
    unsigned de = csr_de[p];
    int d = de & 0xFFFF;
    int r = de >> 16;
    float2 st = ((const float2*)s_t)[d];
    float2 sr = ((const float2*)s_r)[r];
    float sc0 = sh.x + st.x + sr.x;
    float sc1 = sh.y + st.y + sr.y;
    sc0 = (sc0 >= 0.f) ? sc0 : 0.01f * sc0;
    sc1 = (sc1 >= 0.f) ? sc1 : 0.01f * sc1;
    float w0 = __expf(sc0), w1 = __expf(sc1);
    ((float2*)csr_w)[p] = make_float2(w0, w1);
    z0 += w0;
    z1 += w1;
  }
#pragma unroll
  for (int off = 32; off; off >>= 1) {
    z0 += __shfl_xor(z0, off);
    z1 += __shfl_xor(z1, off);
  }
  if (lane == 0) {
    float c0 = (p1 > p0) ? (1.0f - ALPHA) / z0 : 0.f;
    float c1 = (p1 > p0) ? (1.0f - ALPHA) / z1 : 0.f;
    ((float2*)cinv)[n] = make_float2(c0, c1);
  }
}

// ================= monolithic CSR SpMM: wave per node; 4 edge slots x 8 dims/lane =================
template <int IN_H>
__global__ __launch_bounds__(256) void spmm_kernel(
    const int* __restrict__ rowptr, const unsigned* __restrict__ csr_de,
    const float* __restrict__ csr_w, const float* __restrict__ cinv,
    const float* __restrict__ h, const unsigned short* __restrict__ Zin_b,
    unsigned short* __restrict__ Zout_b) {
  int lane = threadIdx.x & 63;
  int slot = lane >> 4;
  int l16 = lane & 15;
  int hh = l16 >> 3;
  int hoff = 8 * (l16 & 7);
  int gw = (blockIdx.x * 256 + threadIdx.x) >> 6;
  int nw = (gridDim.x * 256) >> 6;
  for (int n = gw; n < N_ENT; n += nw) {
    int p0 = rowptr[n], p1 = rowptr[n + 1];
    float acc[8];
#pragma unroll
    for (int j = 0; j < 8; ++j) acc[j] = 0.f;
    for (int p = p0 + slot; p < p1; p += 4) {
      int d = csr_de[p] & 0xFFFF;
      float2 w2 = ((const float2*)csr_w)[p];
      float a = hh ? w2.y : w2.x;
      uv4 q;
      if (IN_H) {
        q = *(const uv4*)(Zin_b + d * 64 + hoff);
      } else {
        q = *(const uv4*)(Zin_b + d * 128 + 8 * l16);
      }
      acc[0] += a * __uint_as_float(q.x << 16);
      acc[1] += a * __uint_as_float(q.x & 0xFFFF0000u);
      acc[2] += a * __uint_as_float(q.y << 16);
      acc[3] += a * __uint_as_float(q.y & 0xFFFF0000u);
      acc[4] += a * __uint_as_float(q.z << 16);
      acc[5] += a * __uint_as_float(q.z & 0xFFFF0000u);
      acc[6] += a * __uint_as_float(q.w << 16);
      acc[7] += a * __uint_as_float(q.w & 0xFFFF0000u);
    }
#pragma unroll
    for (int j = 0; j < 8; ++j) {
      acc[j] += __shfl_xor(acc[j], 16);
      acc[j] += __shfl_xor(acc[j], 32);
    }
    if (slot == 0) {
      float c = cinv[n * 2 + hh];
      const float* hp = h + n * 64 + hoff;
      float o[8];
#pragma unroll
      for (int j = 0; j < 8; ++j) o[j] = ALPHA * hp[j] + c * acc[j];
      uv4 qo;
      qo.x = bf16_rne(o[0]) | (bf16_rne(o[1]) << 16);
      qo.y = bf16_rne(o[2]) | (bf16_rne(o[3]) << 16);
      qo.z = bf16_rne(o[4]) | (bf16_rne(o[5]) << 16);
      qo.w = bf16_rne(o[6]) | (bf16_rne(o[7]) << 16);
      *(uv4*)(Zout_b + n * 128 + 8 * l16) = qo;
    }
  }
}

// ================= output GEMM via MFMA: [50000x128]bf16 @ [128x64]bf16 + x ==============
__global__ __launch_bounds__(256) void out_mfma_kernel(
    const unsigned short* __restrict__ Zb, const float* __restrict__ Wo,
    const float* __restrict__ x, float* __restrict__ out) {
  __shared__ uv4 Bfrag[4][4][64];  // [col-tile][k-step][lane]
  int tid = threadIdx.x;
  for (int idx = tid; idx < 4 * 4 * 64; idx += 256) {
    int ct = idx >> 8, ks = (idx >> 6) & 3, l = idx & 63;
    int col = ct * 16 + (l & 15);
    int kbase = ks * 32 + (l >> 4) * 8;
    unsigned v[8];
#pragma unroll
    for (int j = 0; j < 8; ++j) v[j] = bf16_rne(Wo[(kbase + j) * 64 + col]);
    uv4 q;
    q.x = v[0] | (v[1] << 16);
    q.y = v[2] | (v[3] << 16);
    q.z = v[4] | (v[5] << 16);
    q.w = v[6] | (v[7] << 16);
    Bfrag[ct][ks][l] = q;
  }
  __syncthreads();
  int lane = tid & 63;
  bf16x8 B[4][4];
#pragma unroll
  for (int ct = 0; ct < 4; ++ct)
#pragma unroll
    for (int ks = 0; ks < 4; ++ks) B[ct][ks] = *(bf16x8*)&Bfrag[ct][ks][lane];

  int m = lane & 15;   // node within tile
  int kg = lane >> 4;  // k-group of 8
  int wave = (blockIdx.x * 256 + tid) >> 6;
  int nwaves = (gridDim.x * 256) >> 6;
  const int NT = N_ENT / 16;  // 3125
  for (int t = wave; t < NT; t += nwaves) {
    int n0 = t * 16;
    const unsigned short* zrow = Zb + (size_t)(n0 + m) * 128 + kg * 8;
    bf16x8 A0 = *(const bf16x8*)(zrow);
    bf16x8 A1 = *(const bf16x8*)(zrow + 32);
    bf16x8 A2 = *(const bf16x8*)(zrow + 64);
    bf16x8 A3 = *(const bf16x8*)(zrow + 96);
    f32x4 acc[4];
#pragma unroll
    for (int ct = 0; ct < 4; ++ct) {
      f32x4 a = {0.f, 0.f, 0.f, 0.f};
      a = __builtin_amdgcn_mfma_f32_16x16x32_bf16(A0, B[ct][0], a, 0, 0, 0);
      a = __builtin_amdgcn_mfma_f32_16x16x32_bf16(A1, B[ct][1], a, 0, 0, 0);
      a = __builtin_amdgcn_mfma_f32_16x16x32_bf16(A2, B[ct][2], a, 0, 0, 0);
      a = __builtin_amdgcn_mfma_f32_16x16x32_bf16(A3, B[ct][3], a, 0, 0, 0);
      acc[ct] = a;
    }
#pragma unroll
    for (int r = 0; r < 4; ++r) {
      int rr = n0 + kg * 4 + r;
#pragma unroll
      for (int ct = 0; ct < 4; ++ct) {
        int cc = ct * 16 + (lane & 15);
        out[rr * 64 + cc] = acc[ct][r] + x[rr * 64 + cc];
      }
    }
  }
}

extern "C" void kernel_launch(void* const* d_in, const int* in_sizes, int n_in,
                              void* d_out, int out_size, void* d_ws, size_t ws_size,
                              hipStream_t stream) {
  const float* ent0 = (const float*)d_in[0];
  const float* rel  = (const float*)d_in[1];
  const int* eidx   = (const int*)d_in[2];
  const int* src    = eidx;
  const int* dst    = eidx + N_EDGE;
  const int* et     = (const int*)d_in[3];
  const float* gam  = (const float*)d_in[4];
  const float* bet  = (const float*)d_in[5];
  const float* W_h  = (const float*)d_in[6];
  const float* W_t  = (const float*)d_in[7];
  const float* W_r  = (const float*)d_in[8];
  const float* att_h = (const float*)d_in[9];
  const float* att_t = (const float*)d_in[10];
  const float* att_r = (const float*)d_in[11];
  const float* W_o  = (const float*)d_in[12];
  float* outp = (float*)d_out;

  char* w = (char*)d_ws;
  auto alloc = [&](size_t bytes) {
    char* p = w;
    w += (bytes + 255) & ~(size_t)255;
    return p;
  };
  float* ent1   = (float*)alloc((size_t)N_ENT * 64 * 4);
  float* h      = (float*)alloc((size_t)N_ENT * 64 * 4);
  unsigned short* h_bf = (unsigned short*)alloc((size_t)N_ENT * 64 * 2);
  float* s_h    = (float*)alloc((size_t)N_ENT * 2 * 4);
  float* s_t    = (float*)alloc((size_t)N_ENT * 2 * 4);
  float* s_r    = (float*)alloc((size_t)N_REL * 2 * 4);
  float* cinv   = (float*)alloc((size_t)N_ENT * 2 * 4);
  float* csr_w  = (float*)alloc((size_t)N_EDGE * 2 * 4);
  unsigned short* Zb0 = (unsigned short*)alloc((size_t)N_ENT * 128 * 2);
  unsigned short* Zb1 = (unsigned short*)alloc((size_t)N_ENT * 128 * 2);
  int* deg      = (int*)alloc((size_t)N_ENT * 4);
  int* exc      = (int*)alloc((size_t)N_ENT * 4);
  int* bsum     = (int*)alloc((size_t)NBLK * 4);
  int* boff     = (int*)alloc((size_t)(NBLK + 1) * 4);
  int* rowptr   = (int*)alloc((size_t)(N_ENT + 1) * 4);
  int* cursor   = (int*)alloc((size_t)N_ENT * 4);
  unsigned* csr_de = (unsigned*)alloc((size_t)N_EDGE * 4);

  const int EB = (N_EDGE + 255) / 256;

  // ---- CSR build ----
  hipMemsetAsync(deg, 0, (size_t)N_ENT * 4, stream);
  deg_kernel<<<EB, 256, 0, stream>>>(src, deg);
  scan1_kernel<<<NBLK, 1024, 0, stream>>>(deg, exc, bsum);
  scan2_kernel<<<1, 64, 0, stream>>>(bsum, boff);
  scan3_kernel<<<NBLK, 1024, 0, stream>>>(exc, boff, rowptr);
  hipMemcpyAsync(cursor, rowptr, (size_t)N_ENT * 4, hipMemcpyDeviceToDevice, stream);
  scatter_kernel<<<EB, 256, 0, stream>>>(src, dst, et, cursor, csr_de);

  for (int l = 0; l < 2; ++l) {
    const float* x = (l == 0) ? ent0 : ent1;
    float* y = (l == 0) ? ent1 : outp;

    ln_kernel<<<(N_ENT + 3) / 4, 256, 0, stream>>>(x, gam + l * 64, bet + l * 64, h, h_bf);
    scores2_mfma_kernel<<<392, 256, 0, stream>>>(h_bf, W_h + l * 8192, W_t + l * 8192,
                                                 att_h + l * 128, att_t + l * 128, s_h, s_t);
    scores_kernel<<<8, 256, 0, stream>>>(rel, W_r + l * 8192, att_r + l * 128, s_r, N_REL);

    edge_cinv_kernel<<<(N_ENT + 3) / 4, 256, 0, stream>>>(rowptr, csr_de, s_h, s_t, s_r,
                                                          csr_w, cinv);

    // ---- PPR power iteration: h_bf -> Zb0 -> Zb1 -> Zb0 (all bf16) ----
    spmm_kernel<1><<<2048, 256, 0, stream>>>(rowptr, csr_de, csr_w, cinv, h, h_bf, Zb0);
    spmm_kernel<0><<<2048, 256, 0, stream>>>(rowptr, csr_de, csr_w, cinv, h, Zb0, Zb1);
    spmm_kernel<0><<<2048, 256, 0, stream>>>(rowptr, csr_de, csr_w, cinv, h, Zb1, Zb0);

    out_mfma_kernel<<<512, 256, 0, stream>>>(Zb0, W_o + l * 8192, x, y);
  }
}

// Round 17
// 348.074 us; speedup vs baseline: 1.6733x; 1.0397x over previous
//
#include <hip/hip_runtime.h>

#define N_ENT 50000
#define N_REL 500
#define N_EDGE 500000
#define HEADS 2
#define DIM 64
#define POW_ITER 3
#define ALPHA 0.15f
#define LN_EPS 1e-5f
#define NBLK 49  // ceil(N_ENT/1024)

typedef unsigned uv4 __attribute__((ext_vector_type(4)));
typedef short bf16x8 __attribute__((ext_vector_type(8)));
typedef float f32x4 __attribute__((ext_vector_type(4)));

// bf16 round-to-nearest-even pack
static __device__ __forceinline__ unsigned bf16_rne(float f) {
  unsigned u = __float_as_uint(f);
  return (u + 0x7FFFu + ((u >> 16) & 1u)) >> 16;
}

// branch-free tanh: (e^2x-1)/(e^2x+1), clamped so exp stays finite
static __device__ __forceinline__ float fast_tanh(float x) {
  float xc = fminf(fmaxf(x, -10.f), 10.f);
  float t = __expf(2.f * xc);
  return (t - 1.f) * __builtin_amdgcn_rcpf(t + 1.f);
}

// ================= CSR build (once per launch; graph is layer-invariant) =================
__global__ void deg_kernel(const int* __restrict__ src, int* __restrict__ deg) {
  int e = blockIdx.x * blockDim.x + threadIdx.x;
  if (e >= N_EDGE) return;
  atomicAdd(&deg[src[e]], 1);
}

__global__ __launch_bounds__(1024) void scan1_kernel(const int* __restrict__ deg,
                                                     int* __restrict__ exc,
                                                     int* __restrict__ bsum) {
  __shared__ int tmp[1024];
  int tid = threadIdx.x;
  int i = blockIdx.x * 1024 + tid;
  int v = (i < N_ENT) ? deg[i] : 0;
  tmp[tid] = v;
  __syncthreads();
  for (int off = 1; off < 1024; off <<= 1) {
    int t = (tid >= off) ? tmp[tid - off] : 0;
    __syncthreads();
    tmp[tid] += t;
    __syncthreads();
  }
  if (i < N_ENT) exc[i] = tmp[tid] - v;
  if (tid == 1023) bsum[blockIdx.x] = tmp[1023];
}

__global__ void scan2_kernel(const int* __restrict__ bsum, int* __restrict__ boff) {
  int t = threadIdx.x;  // 64 threads
  int v = (t < NBLK) ? bsum[t] : 0;
  int incl = v;
#pragma unroll
  for (int off = 1; off < 64; off <<= 1) {
    int u = __shfl_up(incl, off);
    if (t >= off) incl += u;
  }
  if (t < NBLK) boff[t] = incl - v;
  if (t == NBLK - 1) boff[NBLK] = incl;
}

__global__ __launch_bounds__(1024) void scan3_kernel(const int* __restrict__ exc,
                                                     const int* __restrict__ boff,
                                                     int* __restrict__ rowptr) {
  int i = blockIdx.x * 1024 + threadIdx.x;
  if (i < N_ENT) rowptr[i] = exc[i] + boff[i >> 10];
  if (i == N_ENT) rowptr[N_ENT] = boff[NBLK];
}

// scatter: csr_de[p] = dst | (et<<16)  (single scattered 4B write per edge)
__global__ void scatter_kernel(const int* __restrict__ src, const int* __restrict__ dst,
                               const int* __restrict__ et, int* __restrict__ cursor,
                               unsigned* __restrict__ csr_de) {
  int e = blockIdx.x * blockDim.x + threadIdx.x;
  if (e >= N_EDGE) return;
  int s = src[e];
  int p = atomicAdd(&cursor[s], 1);
  csr_de[p] = (unsigned)dst[e] | ((unsigned)et[e] << 16);
}

// ================= LayerNorm: one wave per node; writes f32 h and bf16 h_bf =================
__global__ void ln_kernel(const float* __restrict__ x, const float* __restrict__ g,
                          const float* __restrict__ b, float* __restrict__ h,
                          unsigned short* __restrict__ h_bf) {
  int wid = (blockIdx.x * blockDim.x + threadIdx.x) >> 6;
  int lane = threadIdx.x & 63;
  if (wid >= N_ENT) return;
  float v = x[wid * 64 + lane];
  float s = v;
#pragma unroll
  for (int off = 32; off; off >>= 1) s += __shfl_xor(s, off);
  float mu = s * (1.0f / 64.0f);
  float d = v - mu;
  float s2 = d * d;
#pragma unroll
  for (int off = 32; off; off >>= 1) s2 += __shfl_xor(s2, off);
  float rs = rsqrtf(s2 * (1.0f / 64.0f) + LN_EPS);
  float hv = d * rs * g[lane] + b[lane];
  h[wid * 64 + lane] = hv;
  h_bf[wid * 64 + lane] = (unsigned short)bf16_rne(hv);
}

// ================= entity scores via MFMA: T = h@[W_h|W_t], s = sum tanh(T)*att ==========
__global__ __launch_bounds__(256) void scores2_mfma_kernel(
    const unsigned short* __restrict__ h_bf, const float* __restrict__ Wh,
    const float* __restrict__ Wt, const float* __restrict__ ah,
    const float* __restrict__ at, float* __restrict__ s_h, float* __restrict__ s_t) {
  __shared__ uv4 Bfrag[2][8][2][64];  // 32 KB
  int tid = threadIdx.x;
  for (int idx = tid; idx < 2 * 8 * 2 * 64; idx += 256) {
    int l = idx & 63;
    int ks = (idx >> 6) & 1;
    int ct = (idx >> 7) & 7;
    int mat = idx >> 10;
    const float* W = mat ? Wt : Wh;
    int col = ct * 16 + (l & 15);
    int kbase = ks * 32 + (l >> 4) * 8;
    unsigned v[8];
#pragma unroll
    for (int j = 0; j < 8; ++j) v[j] = bf16_rne(W[(kbase + j) * 128 + col]);
    uv4 q;
    q.x = v[0] | (v[1] << 16);
    q.y = v[2] | (v[3] << 16);
    q.z = v[4] | (v[5] << 16);
    q.w = v[6] | (v[7] << 16);
    Bfrag[mat][ct][ks][l] = q;
  }
  __syncthreads();
  int lane = tid & 63;
  int l15 = lane & 15;
  int kg = lane >> 4;
  float attv[2][8];
#pragma unroll
  for (int ct = 0; ct < 8; ++ct) {
    attv[0][ct] = ah[ct * 16 + l15];
    attv[1][ct] = at[ct * 16 + l15];
  }
  int wave = (blockIdx.x * 256 + tid) >> 6;
  int nwaves = (gridDim.x * 256) >> 6;
  const int NT = N_ENT / 16;  // 3125
  for (int t = wave; t < NT; t += nwaves) {
    int n0 = t * 16;
    const unsigned short* zrow = h_bf + (size_t)(n0 + l15) * 64 + kg * 8;
    bf16x8 A0 = *(const bf16x8*)(zrow);
    bf16x8 A1 = *(const bf16x8*)(zrow + 32);
    float ph[2][2][4];
#pragma unroll
    for (int m2 = 0; m2 < 2; ++m2)
#pragma unroll
      for (int hd = 0; hd < 2; ++hd)
#pragma unroll
        for (int r = 0; r < 4; ++r) ph[m2][hd][r] = 0.f;
#pragma unroll
    for (int mat = 0; mat < 2; ++mat) {
#pragma unroll
      for (int ct = 0; ct < 8; ++ct) {
        f32x4 a = {0.f, 0.f, 0.f, 0.f};
        a = __builtin_amdgcn_mfma_f32_16x16x32_bf16(A0, *(bf16x8*)&Bfrag[mat][ct][0][lane], a, 0, 0, 0);
        a = __builtin_amdgcn_mfma_f32_16x16x32_bf16(A1, *(bf16x8*)&Bfrag[mat][ct][1][lane], a, 0, 0, 0);
        int hd = ct >> 2;
        float av = attv[mat][ct];
#pragma unroll
        for (int r = 0; r < 4; ++r) ph[mat][hd][r] += fast_tanh(a[r]) * av;
      }
    }
#pragma unroll
    for (int mat = 0; mat < 2; ++mat)
#pragma unroll
      for (int hd = 0; hd < 2; ++hd)
#pragma unroll
        for (int r = 0; r < 4; ++r) {
          float v = ph[mat][hd][r];
          v += __shfl_xor(v, 1);
          v += __shfl_xor(v, 2);
          v += __shfl_xor(v, 4);
          v += __shfl_xor(v, 8);
          ph[mat][hd][r] = v;
        }
    if (l15 == 0) {
#pragma unroll
      for (int r = 0; r < 4; ++r) {
        int row = n0 + kg * 4 + r;
        ((float2*)s_h)[row] = make_float2(ph[0][0][r], ph[0][1][r]);
        ((float2*)s_t)[row] = make_float2(ph[1][0][r], ph[1][1][r]);
      }
    }
  }
}

// ================= relation scores (small M): W staged in LDS float4; 2 nodes/wave ============
__global__ __launch_bounds__(256) void scores_kernel(
    const float* __restrict__ x, const float* __restrict__ W,
    const float* __restrict__ att, float* __restrict__ s_out, int M) {
  __shared__ float4 WP4[32][64];
  for (int i = threadIdx.x; i < 32 * 64; i += 256) {
    int k2 = i >> 6, j = i & 63;
    WP4[k2][j] = make_float4(W[(2 * k2) * 128 + j], W[(2 * k2) * 128 + j + 64],
                             W[(2 * k2 + 1) * 128 + j], W[(2 * k2 + 1) * 128 + j + 64]);
  }
  __syncthreads();
  int lane = threadIdx.x & 63;
  float a0v = att[lane], a1v = att[lane + 64];
  int gw = (blockIdx.x * 256 + threadIdx.x) >> 6;
  int nw = (gridDim.x * 256) >> 6;
  for (int n0 = 2 * gw; n0 < M; n0 += 2 * nw) {
    int nu = __builtin_amdgcn_readfirstlane(n0);
    const float* xr0 = x + nu * 64;
    const float* xr1 = x + (nu + 1) * 64;
    float a00 = 0.f, a01 = 0.f, a10 = 0.f, a11 = 0.f;
#pragma unroll 8
    for (int k2 = 0; k2 < 32; ++k2) {
      float4 wv = WP4[k2][lane];
      float xa0 = xr0[2 * k2], xa1 = xr0[2 * k2 + 1];
      float xb0 = xr1[2 * k2], xb1 = xr1[2 * k2 + 1];
      a00 += xa0 * wv.x + xa1 * wv.z;
      a01 += xa0 * wv.y + xa1 * wv.w;
      a10 += xb0 * wv.x + xb1 * wv.z;
      a11 += xb0 * wv.y + xb1 * wv.w;
    }
    float t00 = fast_tanh(a00) * a0v, t01 = fast_tanh(a01) * a1v;
    float t10 = fast_tanh(a10) * a0v, t11 = fast_tanh(a11) * a1v;
#pragma unroll
    for (int off = 32; off; off >>= 1) {
      t00 += __shfl_xor(t00, off);
      t01 += __shfl_xor(t01, off);
      t10 += __shfl_xor(t10, off);
      t11 += __shfl_xor(t11, off);
    }
    if (lane == 0) {
      ((float2*)s_out)[nu] = make_float2(t00, t01);
      ((float2*)s_out)[nu + 1] = make_float2(t10, t11);
    }
  }
}

// ================= fused edge weights + cinv: wave per node over contiguous csr_de ===========
__global__ __launch_bounds__(256) void edge_cinv_kernel(
    const int* __restrict__ rowptr, const unsigned* __restrict__ csr_de,
    const float* __restrict__ s_h, const float* __restrict__ s_t,
    const float* __restrict__ s_r, float* __restrict__ csr_w, float* __restrict__ cinv) {
  int n = (blockIdx.x * 256 + threadIdx.x) >> 6;
  int lane = threadIdx.x & 63;
  if (n >= N_ENT) return;
  int p0 = rowptr[n], p1 = rowptr[n + 1];
  float2 sh = ((const float2*)s_h)[n];
  float z0 = 0.f, z1 = 0.f;
  for (int p = p0 + lane; p < p1; p += 64) {
    unsigned de = csr_de[p];
    int d = de & 0xFFFF;
    int r = de >> 16;
    float2 st = ((const float2*)s_t)[d];
    float2 sr = ((const float2*)s_r)[r];
    float sc0 = sh.x + st.x + sr.x;
    float sc1 = sh.y + st.y + sr.y;
    sc0 = (sc0 >= 0.f) ? sc0 : 0.01f * sc0;
    sc1 = (sc1 >= 0.f) ? sc1 : 0.01f * sc1;
    float w0 = __expf(sc0), w1 = __expf(sc1);
    ((float2*)csr_w)[p] = make_float2(w0, w1);
    z0 += w0;
    z1 += w1;
  }
#pragma unroll
  for (int off = 32; off; off >>= 1) {
    z0 += __shfl_xor(z0, off);
    z1 += __shfl_xor(z1, off);
  }
  if (lane == 0) {
    float c0 = (p1 > p0) ? (1.0f - ALPHA) / z0 : 0.f;
    float c1 = (p1 > p0) ? (1.0f - ALPHA) / z1 : 0.f;
    ((float2*)cinv)[n] = make_float2(c0, c1);
  }
}

// ================= monolithic CSR SpMM: wave per node; 4 edge slots x 8 dims/lane ============
// Unroll-by-2 per slot: two independent de->w->Zrow gather chains in flight (8/wave).
template <int IN_H>
__global__ __launch_bounds__(256) void spmm_kernel(
    const int* __restrict__ rowptr, const unsigned* __restrict__ csr_de,
    const float* __restrict__ csr_w, const float* __restrict__ cinv,
    const float* __restrict__ h, const unsigned short* __restrict__ Zin_b,
    unsigned short* __restrict__ Zout_b) {
  int lane = threadIdx.x & 63;
  int slot = lane >> 4;
  int l16 = lane & 15;
  int hh = l16 >> 3;
  int hoff = 8 * (l16 & 7);
  int gw = (blockIdx.x * 256 + threadIdx.x) >> 6;
  int nw = (gridDim.x * 256) >> 6;
  for (int n = gw; n < N_ENT; n += nw) {
    int p0 = rowptr[n], p1 = rowptr[n + 1];
    float acc[8];
#pragma unroll
    for (int j = 0; j < 8; ++j) acc[j] = 0.f;
    int p = p0 + slot;
    for (; p + 4 < p1; p += 8) {
      unsigned de0 = csr_de[p];
      unsigned de1 = csr_de[p + 4];
      float2 wA = ((const float2*)csr_w)[p];
      float2 wB = ((const float2*)csr_w)[p + 4];
      int d0 = de0 & 0xFFFF;
      int d1 = de1 & 0xFFFF;
      uv4 q0, q1;
      if (IN_H) {
        q0 = *(const uv4*)(Zin_b + d0 * 64 + hoff);
        q1 = *(const uv4*)(Zin_b + d1 * 64 + hoff);
      } else {
        q0 = *(const uv4*)(Zin_b + d0 * 128 + 8 * l16);
        q1 = *(const uv4*)(Zin_b + d1 * 128 + 8 * l16);
      }
      float a0 = hh ? wA.y : wA.x;
      float a1 = hh ? wB.y : wB.x;
      acc[0] += a0 * __uint_as_float(q0.x << 16);
      acc[1] += a0 * __uint_as_float(q0.x & 0xFFFF0000u);
      acc[2] += a0 * __uint_as_float(q0.y << 16);
      acc[3] += a0 * __uint_as_float(q0.y & 0xFFFF0000u);
      acc[4] += a0 * __uint_as_float(q0.z << 16);
      acc[5] += a0 * __uint_as_float(q0.z & 0xFFFF0000u);
      acc[6] += a0 * __uint_as_float(q0.w << 16);
      acc[7] += a0 * __uint_as_float(q0.w & 0xFFFF0000u);
      acc[0] += a1 * __uint_as_float(q1.x << 16);
      acc[1] += a1 * __uint_as_float(q1.x & 0xFFFF0000u);
      acc[2] += a1 * __uint_as_float(q1.y << 16);
      acc[3] += a1 * __uint_as_float(q1.y & 0xFFFF0000u);
      acc[4] += a1 * __uint_as_float(q1.z << 16);
      acc[5] += a1 * __uint_as_float(q1.z & 0xFFFF0000u);
      acc[6] += a1 * __uint_as_float(q1.w << 16);
      acc[7] += a1 * __uint_as_float(q1.w & 0xFFFF0000u);
    }
    if (p < p1) {
      unsigned de0 = csr_de[p];
      float2 wA = ((const float2*)csr_w)[p];
      int d0 = de0 & 0xFFFF;
      uv4 q0;
      if (IN_H) {
        q0 = *(const uv4*)(Zin_b + d0 * 64 + hoff);
      } else {
        q0 = *(const uv4*)(Zin_b + d0 * 128 + 8 * l16);
      }
      float a0 = hh ? wA.y : wA.x;
      acc[0] += a0 * __uint_as_float(q0.x << 16);
      acc[1] += a0 * __uint_as_float(q0.x & 0xFFFF0000u);
      acc[2] += a0 * __uint_as_float(q0.y << 16);
      acc[3] += a0 * __uint_as_float(q0.y & 0xFFFF0000u);
      acc[4] += a0 * __uint_as_float(q0.z << 16);
      acc[5] += a0 * __uint_as_float(q0.z & 0xFFFF0000u);
      acc[6] += a0 * __uint_as_float(q0.w << 16);
      acc[7] += a0 * __uint_as_float(q0.w & 0xFFFF0000u);
    }
#pragma unroll
    for (int j = 0; j < 8; ++j) {
      acc[j] += __shfl_xor(acc[j], 16);
      acc[j] += __shfl_xor(acc[j], 32);
    }
    if (slot == 0) {
      float c = cinv[n * 2 + hh];
      const float* hp = h + n * 64 + hoff;
      float o[8];
#pragma unroll
      for (int j = 0; j < 8; ++j) o[j] = ALPHA * hp[j] + c * acc[j];
      uv4 qo;
      qo.x = bf16_rne(o[0]) | (bf16_rne(o[1]) << 16);
      qo.y = bf16_rne(o[2]) | (bf16_rne(o[3]) << 16);
      qo.z = bf16_rne(o[4]) | (bf16_rne(o[5]) << 16);
      qo.w = bf16_rne(o[6]) | (bf16_rne(o[7]) << 16);
      *(uv4*)(Zout_b + n * 128 + 8 * l16) = qo;
    }
  }
}

// ================= output GEMM via MFMA: [50000x128]bf16 @ [128x64]bf16 + x ==============
__global__ __launch_bounds__(256) void out_mfma_kernel(
    const unsigned short* __restrict__ Zb, const float* __restrict__ Wo,
    const float* __restrict__ x, float* __restrict__ out) {
  __shared__ uv4 Bfrag[4][4][64];  // [col-tile][k-step][lane]
  int tid = threadIdx.x;
  for (int idx = tid; idx < 4 * 4 * 64; idx += 256) {
    int ct = idx >> 8, ks = (idx >> 6) & 3, l = idx & 63;
    int col = ct * 16 + (l & 15);
    int kbase = ks * 32 + (l >> 4) * 8;
    unsigned v[8];
#pragma unroll
    for (int j = 0; j < 8; ++j) v[j] = bf16_rne(Wo[(kbase + j) * 64 + col]);
    uv4 q;
    q.x = v[0] | (v[1] << 16);
    q.y = v[2] | (v[3] << 16);
    q.z = v[4] | (v[5] << 16);
    q.w = v[6] | (v[7] << 16);
    Bfrag[ct][ks][l] = q;
  }
  __syncthreads();
  int lane = tid & 63;
  bf16x8 B[4][4];
#pragma unroll
  for (int ct = 0; ct < 4; ++ct)
#pragma unroll
    for (int ks = 0; ks < 4; ++ks) B[ct][ks] = *(bf16x8*)&Bfrag[ct][ks][lane];

  int m = lane & 15;   // node within tile
  int kg = lane >> 4;  // k-group of 8
  int wave = (blockIdx.x * 256 + tid) >> 6;
  int nwaves = (gridDim.x * 256) >> 6;
  const int NT = N_ENT / 16;  // 3125
  for (int t = wave; t < NT; t += nwaves) {
    int n0 = t * 16;
    const unsigned short* zrow = Zb + (size_t)(n0 + m) * 128 + kg * 8;
    bf16x8 A0 = *(const bf16x8*)(zrow);
    bf16x8 A1 = *(const bf16x8*)(zrow + 32);
    bf16x8 A2 = *(const bf16x8*)(zrow + 64);
    bf16x8 A3 = *(const bf16x8*)(zrow + 96);
    f32x4 acc[4];
#pragma unroll
    for (int ct = 0; ct < 4; ++ct) {
      f32x4 a = {0.f, 0.f, 0.f, 0.f};
      a = __builtin_amdgcn_mfma_f32_16x16x32_bf16(A0, B[ct][0], a, 0, 0, 0);
      a = __builtin_amdgcn_mfma_f32_16x16x32_bf16(A1, B[ct][1], a, 0, 0, 0);
      a = __builtin_amdgcn_mfma_f32_16x16x32_bf16(A2, B[ct][2], a, 0, 0, 0);
      a = __builtin_amdgcn_mfma_f32_16x16x32_bf16(A3, B[ct][3], a, 0, 0, 0);
      acc[ct] = a;
    }
#pragma unroll
    for (int r = 0; r < 4; ++r) {
      int rr = n0 + kg * 4 + r;
#pragma unroll
      for (int ct = 0; ct < 4; ++ct) {
        int cc = ct * 16 + (lane & 15);
        out[rr * 64 + cc] = acc[ct][r] + x[rr * 64 + cc];
      }
    }
  }
}

extern "C" void kernel_launch(void* const* d_in, const int* in_sizes, int n_in,
                              void* d_out, int out_size, void* d_ws, size_t ws_size,
                              hipStream_t stream) {
  const float* ent0 = (const float*)d_in[0];
  const float* rel  = (const float*)d_in[1];
  const int* eidx   = (const int*)d_in[2];
  const int* src    = eidx;
  const int* dst    = eidx + N_EDGE;
  const int* et     = (const int*)d_in[3];
  const float* gam  = (const float*)d_in[4];
  const float* bet  = (const float*)d_in[5];
  const float* W_h  = (const float*)d_in[6];
  const float* W_t  = (const float*)d_in[7];
  const float* W_r  = (const float*)d_in[8];
  const float* att_h = (const float*)d_in[9];
  const float* att_t = (const float*)d_in[10];
  const float* att_r = (const float*)d_in[11];
  const float* W_o  = (const float*)d_in[12];
  float* outp = (float*)d_out;

  char* w = (char*)d_ws;
  auto alloc = [&](size_t bytes) {
    char* p = w;
    w += (bytes + 255) & ~(size_t)255;
    return p;
  };
  float* ent1   = (float*)alloc((size_t)N_ENT * 64 * 4);
  float* h      = (float*)alloc((size_t)N_ENT * 64 * 4);
  unsigned short* h_bf = (unsigned short*)alloc((size_t)N_ENT * 64 * 2);
  float* s_h    = (float*)alloc((size_t)N_ENT * 2 * 4);
  float* s_t    = (float*)alloc((size_t)N_ENT * 2 * 4);
  float* s_r    = (float*)alloc((size_t)N_REL * 2 * 4);
  float* cinv   = (float*)alloc((size_t)N_ENT * 2 * 4);
  float* csr_w  = (float*)alloc((size_t)N_EDGE * 2 * 4);
  unsigned short* Zb0 = (unsigned short*)alloc((size_t)N_ENT * 128 * 2);
  unsigned short* Zb1 = (unsigned short*)alloc((size_t)N_ENT * 128 * 2);
  int* deg      = (int*)alloc((size_t)N_ENT * 4);
  int* exc      = (int*)alloc((size_t)N_ENT * 4);
  int* bsum     = (int*)alloc((size_t)NBLK * 4);
  int* boff     = (int*)alloc((size_t)(NBLK + 1) * 4);
  int* rowptr   = (int*)alloc((size_t)(N_ENT + 1) * 4);
  int* cursor   = (int*)alloc((size_t)N_ENT * 4);
  unsigned* csr_de = (unsigned*)alloc((size_t)N_EDGE * 4);

  const int EB = (N_EDGE + 255) / 256;

  // ---- CSR build ----
  hipMemsetAsync(deg, 0, (size_t)N_ENT * 4, stream);
  deg_kernel<<<EB, 256, 0, stream>>>(src, deg);
  scan1_kernel<<<NBLK, 1024, 0, stream>>>(deg, exc, bsum);
  scan2_kernel<<<1, 64, 0, stream>>>(bsum, boff);
  scan3_kernel<<<NBLK, 1024, 0, stream>>>(exc, boff, rowptr);
  hipMemcpyAsync(cursor, rowptr, (size_t)N_ENT * 4, hipMemcpyDeviceToDevice, stream);
  scatter_kernel<<<EB, 256, 0, stream>>>(src, dst, et, cursor, csr_de);

  for (int l = 0; l < 2; ++l) {
    const float* x = (l == 0) ? ent0 : ent1;
    float* y = (l == 0) ? ent1 : outp;

    ln_kernel<<<(N_ENT + 3) / 4, 256, 0, stream>>>(x, gam + l * 64, bet + l * 64, h, h_bf);
    scores2_mfma_kernel<<<392, 256, 0, stream>>>(h_bf, W_h + l * 8192, W_t + l * 8192,
                                                 att_h + l * 128, att_t + l * 128, s_h, s_t);
    scores_kernel<<<8, 256, 0, stream>>>(rel, W_r + l * 8192, att_r + l * 128, s_r, N_REL);

    edge_cinv_kernel<<<(N_ENT + 3) / 4, 256, 0, stream>>>(rowptr, csr_de, s_h, s_t, s_r,
                                                          csr_w, cinv);

    // ---- PPR power iteration: h_bf -> Zb0 -> Zb1 -> Zb0 (all bf16) ----
    spmm_kernel<1><<<2048, 256, 0, stream>>>(rowptr, csr_de, csr_w, cinv, h, h_bf, Zb0);
    spmm_kernel<0><<<2048, 256, 0, stream>>>(rowptr, csr_de, csr_w, cinv, h, Zb0, Zb1);
    spmm_kernel<0><<<2048, 256, 0, stream>>>(rowptr, csr_de, csr_w, cinv, h, Zb1, Zb0);

    out_mfma_kernel<<<512, 256, 0, stream>>>(Zb0, W_o + l * 8192, x, y);
  }
}